// Round 1
// baseline (1335.354 us; speedup 1.0000x reference)
//
#include <hip/hip_runtime.h>
#include <math.h>

#define NPTS 16384
#define BGR 16
#define NPGR 1024
#define KNN 12
#define DM 128
#define DH 256
#define NL 3
#define EDG (NPTS*KNN)

__device__ __forceinline__ float silu_f(float x) {
    return x / (1.0f + __expf(-x));
}

// ---------------------------------------------------------------- KNN + edge attrs
__global__ __launch_bounds__(256) void knn_kernel(const float* __restrict__ x,
                                                  int* __restrict__ srcb,
                                                  float* __restrict__ ea) {
#pragma clang fp contract(off)
    __shared__ float px[NPGR], py[NPGR], s0[NPGR];
    int g = blockIdx.x >> 2;
    int quarter = blockIdx.x & 3;
    int t = threadIdx.x;
    int base = g * NPGR;
    for (int j = t; j < NPGR; j += 256) {
        const float* xp = x + (size_t)(base + j) * 3;
        s0[j] = xp[0]; px[j] = xp[1]; py[j] = xp[2];
    }
    __syncthreads();
    int il = quarter * 256 + t;
    float xi = px[il], yi = py[il];
    float nd[KNN]; int ni[KNN];
#pragma unroll
    for (int k = 0; k < KNN; ++k) { nd[k] = 3.4e38f; ni[k] = 0; }
    for (int j = 0; j < NPGR; ++j) {
        if (j == il) continue;
        float dx = px[j] - xi;
        float dy = py[j] - yi;
        float dx2 = dx * dx;
        float dy2 = dy * dy;
        float d2 = dx2 + dy2;
        if (d2 < nd[KNN-1]) {
            // stable sorted insertion (ascending d2, earlier index wins ties)
            float cd = d2; int ci = j;
#pragma unroll
            for (int k = 0; k < KNN; ++k) {
                bool sw = cd < nd[k];
                float tdv = sw ? nd[k] : cd;
                nd[k] = sw ? cd : nd[k];
                cd = tdv;
                int tiv = sw ? ni[k] : ci;
                ni[k] = sw ? ci : ni[k];
                ci = tiv;
            }
        }
    }
    float x0i = s0[il];
#pragma unroll
    for (int k = 0; k < KNN; ++k) {
        int j = ni[k];
        size_t e = (size_t)(base + il) * KNN + k;
        srcb[e] = base + j;
        float dpx = px[j] - xi, dpy = py[j] - yi;
        float a = dpx * dpx;
        float b = dpy * dpy;
        float dist = sqrtf(a + b + 1e-12f);
        float dsv = s0[j] - x0i;
        *(float4*)(ea + e * 4) = make_float4(dpx, dpy, dist, dsv);
    }
}

// ---------------------------------------------------------------- input MLP (K=3 then 128x128), 8 nodes/block
__global__ __launch_bounds__(128) void in_mlp_kernel(const float* __restrict__ x,
    const float* __restrict__ W1, const float* __restrict__ b1,
    const float* __restrict__ W2, const float* __restrict__ b2,
    float* __restrict__ h) {
    __shared__ float hid[8][DM];
    __shared__ float xl[8][3];
    int t = threadIdx.x;
    int nb = blockIdx.x * 8;
    if (t < 24) xl[t / 3][t % 3] = x[(size_t)nb * 3 + t];
    __syncthreads();
    float w0 = W1[t], w1 = W1[DM + t], w2 = W1[2 * DM + t], bb = b1[t];
#pragma unroll
    for (int gi = 0; gi < 8; ++gi) {
        float v = xl[gi][0] * w0 + xl[gi][1] * w1 + xl[gi][2] * w2 + bb;
        hid[gi][t] = silu_f(v);
    }
    __syncthreads();
    float acc[8];
    float b2v = b2[t];
#pragma unroll
    for (int gi = 0; gi < 8; ++gi) acc[gi] = b2v;
    for (int k = 0; k < DM; ++k) {
        float w = W2[k * DM + t];
#pragma unroll
        for (int gi = 0; gi < 8; ++gi) acc[gi] += hid[gi][k] * w;
    }
#pragma unroll
    for (int gi = 0; gi < 8; ++gi) h[(size_t)(nb + gi) * DM + t] = acc[gi];
}

// ---------------------------------------------------------------- generic fp32 GEMM
// out[n][c] = act( [A0|A1](n,:) @ [B0;B1](:,c) + bias[c] ) + resid[n][c]
// A = concat along K of A0 (k0 cols) and A1 (k1 cols); B rows 0..k0-1 from B0, k0.. from B1.
#define BM 64
#define BN 128
#define BK 16
#define AS_LD 68

__global__ __launch_bounds__(256) void gemm_kernel(
    const float* __restrict__ A0, int k0, int lda0,
    const float* __restrict__ A1, int k1, int lda1,
    const float* __restrict__ B0, int ldb0,
    const float* __restrict__ B1, int ldb1,
    const float* __restrict__ bias,
    const float* __restrict__ resid, int ldres,
    float* __restrict__ out, int ldout,
    int act)
{
    __shared__ float As[BK * AS_LD];
    __shared__ float Bs[BK * BN];
    int t = threadIdx.x;
    int row0 = blockIdx.x * BM;
    int col0 = blockIdx.y * BN;
    int tc = t & 15, tr = t >> 4;
    int r0 = tr * 4, c0 = tc * 8;
    float acc[4][8];
#pragma unroll
    for (int i = 0; i < 4; ++i)
#pragma unroll
        for (int j = 0; j < 8; ++j) acc[i][j] = 0.f;

    int K = k0 + k1;
    int ar = t >> 2, aq = t & 3;          // A staging: row ar, float4 #aq
    int bk0 = t >> 5, bc0 = (t & 31) * 4; // B staging

    for (int kt = 0; kt < K; kt += BK) {
        const float* Ap;
        if (kt < k0) Ap = A0 + (size_t)(row0 + ar) * lda0 + kt;
        else         Ap = A1 + (size_t)(row0 + ar) * lda1 + (kt - k0);
        float4 av = *(const float4*)(Ap + aq * 4);
        As[(aq * 4 + 0) * AS_LD + ar] = av.x;
        As[(aq * 4 + 1) * AS_LD + ar] = av.y;
        As[(aq * 4 + 2) * AS_LD + ar] = av.z;
        As[(aq * 4 + 3) * AS_LD + ar] = av.w;
#pragma unroll
        for (int h2 = 0; h2 < 2; ++h2) {
            int kk = kt + bk0 + h2 * 8;
            const float* Bp = (kk < k0) ? (B0 + (size_t)kk * ldb0)
                                        : (B1 + (size_t)(kk - k0) * ldb1);
            float4 bv = *(const float4*)(Bp + col0 + bc0);
            *(float4*)(Bs + (bk0 + h2 * 8) * BN + bc0) = bv;
        }
        __syncthreads();
#pragma unroll
        for (int k = 0; k < BK; ++k) {
            float4 a  = *(const float4*)(As + k * AS_LD + r0);
            float4 b0v = *(const float4*)(Bs + k * BN + c0);
            float4 b1v = *(const float4*)(Bs + k * BN + c0 + 4);
            float aa[4] = {a.x, a.y, a.z, a.w};
            float bb[8] = {b0v.x, b0v.y, b0v.z, b0v.w, b1v.x, b1v.y, b1v.z, b1v.w};
#pragma unroll
            for (int i = 0; i < 4; ++i)
#pragma unroll
                for (int j = 0; j < 8; ++j) acc[i][j] += aa[i] * bb[j];
        }
        __syncthreads();
    }
#pragma unroll
    for (int i = 0; i < 4; ++i) {
        int r = row0 + r0 + i;
        float* op = out + (size_t)r * ldout + col0 + c0;
        const float* rp = resid ? (resid + (size_t)r * ldres + col0 + c0) : nullptr;
#pragma unroll
        for (int j = 0; j < 8; ++j) {
            float v = acc[i][j];
            if (bias) v += bias[col0 + c0 + j];
            if (act == 1) v = silu_f(v);
            if (rp) v += rp[j];
            op[j] = v;
        }
    }
}

// ---------------------------------------------------------------- per-node edge aggregation (gather + silu sum)
// HS[i][t] = sum_e silu( C[i][t] + S[src_e][t] + ea_e . W1ea[:,t] )
__global__ __launch_bounds__(256) void edge_agg_kernel(
    const float* __restrict__ C, const float* __restrict__ S,
    const int* __restrict__ srcb, const float* __restrict__ ea,
    const float* __restrict__ W1ea,
    float* __restrict__ HS)
{
    int i = blockIdx.x, t = threadIdx.x;
    __shared__ int ss[KNN];
    __shared__ float sea[KNN * 4];
    if (t < KNN) ss[t] = srcb[(size_t)i * KNN + t];
    if (t < KNN * 4) sea[t] = ea[(size_t)i * KNN * 4 + t];
    __syncthreads();
    float base = C[(size_t)i * DH + t];
    float wa = W1ea[t], wb = W1ea[DH + t], wc = W1ea[2 * DH + t], wd = W1ea[3 * DH + t];
    float hs = 0.f;
#pragma unroll
    for (int e = 0; e < KNN; ++e) {
        float v = base + S[(size_t)ss[e] * DH + t]
                + sea[e * 4 + 0] * wa + sea[e * 4 + 1] * wb
                + sea[e * 4 + 2] * wc + sea[e * 4 + 3] * wd;
        hs += silu_f(v);
    }
    HS[(size_t)i * DH + t] = hs;
}

// ---------------------------------------------------------------- graph norm (one block per graph)
__global__ __launch_bounds__(256) void norm_kernel(
    const float* __restrict__ hn, float* __restrict__ h,
    const float* __restrict__ w, const float* __restrict__ b, const float* __restrict__ ms)
{
    int g = blockIdx.x, t = threadIdx.x;
    int d = t & 127, half = t >> 7;
    size_t base = (size_t)g * NPGR * DM;
    __shared__ float part[2][DM];
    __shared__ float meanv[DM], rstdv[DM], wv[DM], bv[DM], msv[DM];
    if (t < DM) { wv[t] = w[t]; bv[t] = b[t]; msv[t] = ms[t]; }
    float s = 0.f;
    for (int n = half * 512; n < half * 512 + 512; ++n) s += hn[base + (size_t)n * DM + d];
    part[half][d] = s;
    __syncthreads();
    if (t < DM) meanv[t] = (part[0][t] + part[1][t]) * (1.0f / NPGR);
    __syncthreads();
    float m = meanv[d] * msv[d];
    float s2 = 0.f;
    for (int n = half * 512; n < half * 512 + 512; ++n) {
        float o = hn[base + (size_t)n * DM + d] - m;
        s2 += o * o;
    }
    part[half][d] = s2;
    __syncthreads();
    if (t < DM) {
        float var = (part[0][t] + part[1][t]) * (1.0f / NPGR);
        rstdv[t] = 1.0f / sqrtf(var + 1e-5f);
    }
    __syncthreads();
    for (int idx = t; idx < NPGR * DM; idx += 256) {
        int dd = idx & 127;
        float o = hn[base + idx] - meanv[dd] * msv[dd];
        h[base + idx] = wv[dd] * o * rstdv[dd] + bv[dd];
    }
}

// ---------------------------------------------------------------- gate scalar per node, 8 nodes/block
__global__ __launch_bounds__(128) void gate_kernel(
    const float* __restrict__ h,
    const float* __restrict__ gW1, const float* __restrict__ gb1,
    const float* __restrict__ gW2, const float* __restrict__ gb2,
    float* __restrict__ gl)
{
    __shared__ float hh[8][DM];
    __shared__ float hid[8][DM];
    __shared__ float partial[2][8];
    int t = threadIdx.x;
    int nb = blockIdx.x * 8;
    for (int idx = t; idx < 8 * DM; idx += 128) hh[idx >> 7][idx & 127] = h[(size_t)nb * DM + idx];
    __syncthreads();
    float acc[8];
    float bb = gb1[t];
#pragma unroll
    for (int gi = 0; gi < 8; ++gi) acc[gi] = bb;
    for (int k = 0; k < DM; ++k) {
        float w = gW1[k * DM + t];
#pragma unroll
        for (int gi = 0; gi < 8; ++gi) acc[gi] += hh[gi][k] * w;
    }
#pragma unroll
    for (int gi = 0; gi < 8; ++gi) hid[gi][t] = tanhf(acc[gi]);
    __syncthreads();
    float w2 = gW2[t];
    int lane = t & 63, wv = t >> 6;
#pragma unroll
    for (int gi = 0; gi < 8; ++gi) {
        float v = hid[gi][t] * w2;
        for (int off = 32; off > 0; off >>= 1) v += __shfl_down(v, off, 64);
        if (lane == 0) partial[wv][gi] = v;
    }
    __syncthreads();
    if (t < 8) gl[nb + t] = partial[0][t] + partial[1][t] + gb2[0];
}

// ---------------------------------------------------------------- softmax pool + head (one block per graph)
__global__ __launch_bounds__(256) void pool_head_kernel(
    const float* __restrict__ h, const float* __restrict__ gl,
    const float* __restrict__ hW1, const float* __restrict__ hb1,
    const float* __restrict__ hW2, const float* __restrict__ hb2,
    float* __restrict__ outp)
{
    int g = blockIdx.x, t = threadIdx.x;
    __shared__ float red[4];
    __shared__ float el[NPGR];
    __shared__ float pl[DM];
    __shared__ float part[2][DM];
    __shared__ float hd[DM];
    size_t gbase = (size_t)g * NPGR;
    int lane = t & 63, wv = t >> 6;
    float mx = -3.4e38f;
    for (int n = t; n < NPGR; n += 256) mx = fmaxf(mx, gl[gbase + n]);
    for (int off = 32; off > 0; off >>= 1) mx = fmaxf(mx, __shfl_down(mx, off, 64));
    if (lane == 0) red[wv] = mx;
    __syncthreads();
    if (t == 0) red[0] = fmaxf(fmaxf(red[0], red[1]), fmaxf(red[2], red[3]));
    __syncthreads();
    float gmax = red[0];
    __syncthreads();
    float se = 0.f;
    for (int n = t; n < NPGR; n += 256) {
        float e = __expf(gl[gbase + n] - gmax);
        el[n] = e;
        se += e;
    }
    for (int off = 32; off > 0; off >>= 1) se += __shfl_down(se, off, 64);
    if (lane == 0) red[wv] = se;
    __syncthreads();
    float ssum = red[0] + red[1] + red[2] + red[3];
    int d = t & 127, half = t >> 7;
    float p = 0.f;
    for (int n = half * 512; n < half * 512 + 512; ++n) p += el[n] * h[(gbase + n) * DM + d];
    part[half][d] = p;
    __syncthreads();
    if (t < DM) pl[t] = (part[0][t] + part[1][t]) / ssum;
    __syncthreads();
    if (t < DM) {
        float a = hb1[t];
        for (int k = 0; k < DM; ++k) a += pl[k] * hW1[k * DM + t];
        hd[t] = silu_f(a);
    }
    __syncthreads();
    float vv = (t < DM) ? hd[t] * hW2[t] : 0.f;
    for (int off = 32; off > 0; off >>= 1) vv += __shfl_down(vv, off, 64);
    if (lane == 0) red[wv] = vv;
    __syncthreads();
    if (t == 0) outp[g] = red[0] + red[1] + red[2] + red[3] + hb2[0];
}

// ---------------------------------------------------------------- per-layer constants: W2U = msgW2 @ U1_bot ; bias2 = ub1 + 12*b2@U1_bot
__global__ __launch_bounds__(256) void precompute_kernel(
    const float* __restrict__ msgW2, const float* __restrict__ msgb2,
    const float* __restrict__ updW1, const float* __restrict__ updb1,
    float* __restrict__ W2U, float* __restrict__ bias2)
{
    int bid = blockIdx.x; int t = threadIdx.x;
    if (bid < NL * DH) {
        int l = bid / DH, k = bid % DH;
        const float* w2row = msgW2 + (size_t)l * DH * DM + (size_t)k * DM;
        const float* u1 = updW1 + (size_t)l * 2 * DM * DH;
        float acc = 0.f;
        for (int j = 0; j < DM; ++j) acc += w2row[j] * u1[(size_t)(DM + j) * DH + t];
        W2U[(size_t)l * DH * DH + (size_t)k * DH + t] = acc;
    } else {
        int l = bid - NL * DH;
        const float* u1 = updW1 + (size_t)l * 2 * DM * DH;
        const float* b2 = msgb2 + (size_t)l * DM;
        float acc = updb1[(size_t)l * DH + t];
        for (int j = 0; j < DM; ++j) acc += 12.0f * b2[j] * u1[(size_t)(DM + j) * DH + t];
        bias2[(size_t)l * DH + t] = acc;
    }
}

extern "C" void kernel_launch(void* const* d_in, const int* in_sizes, int n_in,
                              void* d_out, int out_size, void* d_ws, size_t ws_size,
                              hipStream_t stream) {
    const float* x     = (const float*)d_in[0];
    const float* inW1  = (const float*)d_in[2];
    const float* inb1  = (const float*)d_in[3];
    const float* inW2  = (const float*)d_in[4];
    const float* inb2  = (const float*)d_in[5];
    const float* msgW1 = (const float*)d_in[6];
    const float* msgb1 = (const float*)d_in[7];
    const float* msgW2 = (const float*)d_in[8];
    const float* msgb2 = (const float*)d_in[9];
    const float* updW1 = (const float*)d_in[10];
    const float* updb1 = (const float*)d_in[11];
    const float* updW2 = (const float*)d_in[12];
    const float* updb2 = (const float*)d_in[13];
    const float* nw    = (const float*)d_in[14];
    const float* nb    = (const float*)d_in[15];
    const float* nms   = (const float*)d_in[16];
    const float* gW1   = (const float*)d_in[17];
    const float* gb1   = (const float*)d_in[18];
    const float* gW2   = (const float*)d_in[19];
    const float* gb2   = (const float*)d_in[20];
    const float* hW1   = (const float*)d_in[21];
    const float* hb1   = (const float*)d_in[22];
    const float* hW2   = (const float*)d_in[23];
    const float* hb2   = (const float*)d_in[24];
    float* outp = (float*)d_out;

    float* ws   = (float*)d_ws;
    float* h    = ws;                          // N*DM
    float* Cb   = h + (size_t)NPTS * DM;       // N*DH (also reused as T)
    float* Sb   = Cb + (size_t)NPTS * DH;      // N*DH (also reused as hn)
    float* HSb  = Sb + (size_t)NPTS * DH;      // N*DH
    float* W2U  = HSb + (size_t)NPTS * DH;     // 3*DH*DH
    float* bias2 = W2U + (size_t)NL * DH * DH; // 3*DH
    float* glb  = bias2 + NL * DH;             // N
    int* srcb   = (int*)(glb + NPTS);          // E ints
    float* eab  = (float*)(srcb + EDG);        // E*4

    hipLaunchKernelGGL(precompute_kernel, dim3(NL * DH + NL), dim3(DH), 0, stream,
                       msgW2, msgb2, updW1, updb1, W2U, bias2);
    hipLaunchKernelGGL(knn_kernel, dim3(BGR * 4), dim3(256), 0, stream, x, srcb, eab);
    hipLaunchKernelGGL(in_mlp_kernel, dim3(NPTS / 8), dim3(128), 0, stream,
                       x, inW1, inb1, inW2, inb2, h);

    for (int l = 0; l < NL; ++l) {
        const float* W1l = msgW1 + (size_t)l * (2 * DM + 4) * DH;
        // C = h @ W1[0:128] + msg_b1
        hipLaunchKernelGGL(gemm_kernel, dim3(NPTS / BM, DH / BN), dim3(256), 0, stream,
            h, DM, DM, (const float*)nullptr, 0, 0,
            W1l, DH, (const float*)nullptr, 0,
            msgb1 + (size_t)l * DH, (const float*)nullptr, 0,
            Cb, DH, 0);
        // S = h @ W1[128:256]
        hipLaunchKernelGGL(gemm_kernel, dim3(NPTS / BM, DH / BN), dim3(256), 0, stream,
            h, DM, DM, (const float*)nullptr, 0, 0,
            W1l + (size_t)DM * DH, DH, (const float*)nullptr, 0,
            (const float*)nullptr, (const float*)nullptr, 0,
            Sb, DH, 0);
        // HS[i] = sum_e silu(C[i] + S[src] + ea.W1ea)
        hipLaunchKernelGGL(edge_agg_kernel, dim3(NPTS), dim3(DH), 0, stream,
            Cb, Sb, srcb, eab, W1l + (size_t)2 * DM * DH, HSb);
        // T = silu(h@U1top + HS@W2U + bias2)  (into Cb)
        hipLaunchKernelGGL(gemm_kernel, dim3(NPTS / BM, DH / BN), dim3(256), 0, stream,
            h, DM, DM, HSb, DH, DH,
            updW1 + (size_t)l * 2 * DM * DH, DH, W2U + (size_t)l * DH * DH, DH,
            bias2 + (size_t)l * DH, (const float*)nullptr, 0,
            Cb, DH, 1);
        // hn = h + T@U2 + upd_b2  (into Sb)
        hipLaunchKernelGGL(gemm_kernel, dim3(NPTS / BM, DM / BN), dim3(256), 0, stream,
            Cb, DH, DH, (const float*)nullptr, 0, 0,
            updW2 + (size_t)l * DH * DM, DM, (const float*)nullptr, 0,
            updb2 + (size_t)l * DM, h, DM,
            Sb, DM, 0);
        // h = graph_norm(hn)
        hipLaunchKernelGGL(norm_kernel, dim3(BGR), dim3(256), 0, stream,
            Sb, h, nw + (size_t)l * DM, nb + (size_t)l * DM, nms + (size_t)l * DM);
    }

    hipLaunchKernelGGL(gate_kernel, dim3(NPTS / 8), dim3(128), 0, stream,
                       h, gW1, gb1, gW2, gb2, glb);
    hipLaunchKernelGGL(pool_head_kernel, dim3(BGR), dim3(256), 0, stream,
                       h, glb, hW1, hb1, hW2, hb2, outp);
}

// Round 2
// 1096.865 us; speedup vs baseline: 1.2174x; 1.2174x over previous
//
#include <hip/hip_runtime.h>
#include <math.h>

#define NPTS 16384
#define BGR 16
#define NPGR 1024
#define KNN 12
#define DM 128
#define DH 256
#define NL 3
#define EDG (NPTS*KNN)

__device__ __forceinline__ float silu_f(float x) {
    return x / (1.0f + __expf(-x));
}

// ---------------------------------------------------------------- KNN + edge attrs
// 64 points per block, 4 threads per point each scanning a 256-candidate
// quarter with a private stable top-12; 4-way sorted merge in LDS with
// (d2, index) tie-break reproduces the global stable insertion order.
#define PPB 64
__global__ __launch_bounds__(256) void knn_kernel(const float* __restrict__ x,
                                                  int* __restrict__ srcb,
                                                  float* __restrict__ ea) {
#pragma clang fp contract(off)
    __shared__ float px[NPGR], py[NPGR], s0[NPGR];
    __shared__ float sd[PPB][4][KNN];
    __shared__ int   si[PPB][4][KNN];
    __shared__ int   sel[PPB][KNN];
    int t = threadIdx.x;
    int g   = blockIdx.x / (NPGR / PPB);
    int blk = blockIdx.x % (NPGR / PPB);
    int base = g * NPGR;
    for (int j = t; j < NPGR; j += 256) {
        const float* xp = x + (size_t)(base + j) * 3;
        s0[j] = xp[0]; px[j] = xp[1]; py[j] = xp[2];
    }
    __syncthreads();
    int r  = t >> 6;       // candidate quarter 0..3
    int pt = t & 63;       // point within block
    int il = blk * PPB + pt;
    float xi = px[il], yi = py[il];
    float nd[KNN]; int ni[KNN];
#pragma unroll
    for (int k = 0; k < KNN; ++k) { nd[k] = 3.4e38f; ni[k] = 0x7fffffff; }
    int j0 = r * 256;
    for (int jj = 0; jj < 256; ++jj) {
        int j = j0 + jj;
        if (j == il) continue;
        float dx = px[j] - xi;
        float dy = py[j] - yi;
        float dx2 = dx * dx;
        float dy2 = dy * dy;
        float d2 = dx2 + dy2;
        if (d2 < nd[KNN-1]) {
            float cd = d2; int ci = j;
#pragma unroll
            for (int k = 0; k < KNN; ++k) {
                bool sw = cd < nd[k];
                float tdv = sw ? nd[k] : cd;
                nd[k] = sw ? cd : nd[k];
                cd = tdv;
                int tiv = sw ? ni[k] : ci;
                ni[k] = sw ? ci : ni[k];
                ci = tiv;
            }
        }
    }
#pragma unroll
    for (int k = 0; k < KNN; ++k) { sd[pt][r][k] = nd[k]; si[pt][r][k] = ni[k]; }
    __syncthreads();
    if (r == 0) {
        int head[4] = {0, 0, 0, 0};
#pragma unroll
        for (int k = 0; k < KNN; ++k) {
            float bd = 3.4e38f; int bi = 0x7fffffff; int bq = 0;
#pragma unroll
            for (int q = 0; q < 4; ++q) {
                int hq = head[q];
                float d = (hq < KNN) ? sd[pt][q][hq] : 3.4e38f;
                int  ix = (hq < KNN) ? si[pt][q][hq] : 0x7fffffff;
                if (d < bd || (d == bd && ix < bi)) { bd = d; bi = ix; bq = q; }
            }
            head[bq]++;
            sel[pt][k] = bi;
        }
    }
    __syncthreads();
    float x0i = s0[il];
#pragma unroll
    for (int kk = 0; kk < 3; ++kk) {
        int k = r * 3 + kk;
        int j = sel[pt][k];
        size_t e = (size_t)(base + il) * KNN + k;
        srcb[e] = base + j;
        float dpx = px[j] - xi, dpy = py[j] - yi;
        float a = dpx * dpx;
        float b = dpy * dpy;
        float dist = sqrtf(a + b + 1e-12f);
        float dsv = s0[j] - x0i;
        *(float4*)(ea + e * 4) = make_float4(dpx, dpy, dist, dsv);
    }
}

// ---------------------------------------------------------------- input MLP (K=3 then 128x128), 8 nodes/block
__global__ __launch_bounds__(128) void in_mlp_kernel(const float* __restrict__ x,
    const float* __restrict__ W1, const float* __restrict__ b1,
    const float* __restrict__ W2, const float* __restrict__ b2,
    float* __restrict__ h) {
    __shared__ float hid[8][DM];
    __shared__ float xl[8][3];
    int t = threadIdx.x;
    int nb = blockIdx.x * 8;
    if (t < 24) xl[t / 3][t % 3] = x[(size_t)nb * 3 + t];
    __syncthreads();
    float w0 = W1[t], w1 = W1[DM + t], w2 = W1[2 * DM + t], bb = b1[t];
#pragma unroll
    for (int gi = 0; gi < 8; ++gi) {
        float v = xl[gi][0] * w0 + xl[gi][1] * w1 + xl[gi][2] * w2 + bb;
        hid[gi][t] = silu_f(v);
    }
    __syncthreads();
    float acc[8];
    float b2v = b2[t];
#pragma unroll
    for (int gi = 0; gi < 8; ++gi) acc[gi] = b2v;
    for (int k = 0; k < DM; ++k) {
        float w = W2[k * DM + t];
#pragma unroll
        for (int gi = 0; gi < 8; ++gi) acc[gi] += hid[gi][k] * w;
    }
#pragma unroll
    for (int gi = 0; gi < 8; ++gi) h[(size_t)(nb + gi) * DM + t] = acc[gi];
}

// ---------------------------------------------------------------- generic fp32 GEMM
#define BM 64
#define BN 128
#define BK 16
#define AS_LD 68

__global__ __launch_bounds__(256) void gemm_kernel(
    const float* __restrict__ A0, int k0, int lda0,
    const float* __restrict__ A1, int k1, int lda1,
    const float* __restrict__ B0, int ldb0,
    const float* __restrict__ B1, int ldb1,
    const float* __restrict__ bias,
    const float* __restrict__ resid, int ldres,
    float* __restrict__ out, int ldout,
    int act)
{
    __shared__ float As[BK * AS_LD];
    __shared__ float Bs[BK * BN];
    int t = threadIdx.x;
    int row0 = blockIdx.x * BM;
    int col0 = blockIdx.y * BN;
    int tc = t & 15, tr = t >> 4;
    int r0 = tr * 4, c0 = tc * 8;
    float acc[4][8];
#pragma unroll
    for (int i = 0; i < 4; ++i)
#pragma unroll
        for (int j = 0; j < 8; ++j) acc[i][j] = 0.f;

    int K = k0 + k1;
    int ar = t >> 2, aq = t & 3;
    int bk0 = t >> 5, bc0 = (t & 31) * 4;

    for (int kt = 0; kt < K; kt += BK) {
        const float* Ap;
        if (kt < k0) Ap = A0 + (size_t)(row0 + ar) * lda0 + kt;
        else         Ap = A1 + (size_t)(row0 + ar) * lda1 + (kt - k0);
        float4 av = *(const float4*)(Ap + aq * 4);
        As[(aq * 4 + 0) * AS_LD + ar] = av.x;
        As[(aq * 4 + 1) * AS_LD + ar] = av.y;
        As[(aq * 4 + 2) * AS_LD + ar] = av.z;
        As[(aq * 4 + 3) * AS_LD + ar] = av.w;
#pragma unroll
        for (int h2 = 0; h2 < 2; ++h2) {
            int kk = kt + bk0 + h2 * 8;
            const float* Bp = (kk < k0) ? (B0 + (size_t)kk * ldb0)
                                        : (B1 + (size_t)(kk - k0) * ldb1);
            float4 bv = *(const float4*)(Bp + col0 + bc0);
            *(float4*)(Bs + (bk0 + h2 * 8) * BN + bc0) = bv;
        }
        __syncthreads();
#pragma unroll
        for (int k = 0; k < BK; ++k) {
            float4 a  = *(const float4*)(As + k * AS_LD + r0);
            float4 b0v = *(const float4*)(Bs + k * BN + c0);
            float4 b1v = *(const float4*)(Bs + k * BN + c0 + 4);
            float aa[4] = {a.x, a.y, a.z, a.w};
            float bb[8] = {b0v.x, b0v.y, b0v.z, b0v.w, b1v.x, b1v.y, b1v.z, b1v.w};
#pragma unroll
            for (int i = 0; i < 4; ++i)
#pragma unroll
                for (int j = 0; j < 8; ++j) acc[i][j] += aa[i] * bb[j];
        }
        __syncthreads();
    }
#pragma unroll
    for (int i = 0; i < 4; ++i) {
        int r = row0 + r0 + i;
        float* op = out + (size_t)r * ldout + col0 + c0;
        const float* rp = resid ? (resid + (size_t)r * ldres + col0 + c0) : nullptr;
#pragma unroll
        for (int j = 0; j < 8; ++j) {
            float v = acc[i][j];
            if (bias) v += bias[col0 + c0 + j];
            if (act == 1) v = silu_f(v);
            if (rp) v += rp[j];
            op[j] = v;
        }
    }
}

// ---------------------------------------------------------------- per-node edge aggregation (gather + silu sum)
__global__ __launch_bounds__(256) void edge_agg_kernel(
    const float* __restrict__ C, const float* __restrict__ S,
    const int* __restrict__ srcb, const float* __restrict__ ea,
    const float* __restrict__ W1ea,
    float* __restrict__ HS)
{
    int i = blockIdx.x, t = threadIdx.x;
    __shared__ int ss[KNN];
    __shared__ float sea[KNN * 4];
    if (t < KNN) ss[t] = srcb[(size_t)i * KNN + t];
    if (t < KNN * 4) sea[t] = ea[(size_t)i * KNN * 4 + t];
    __syncthreads();
    float base = C[(size_t)i * DH + t];
    float wa = W1ea[t], wb = W1ea[DH + t], wc = W1ea[2 * DH + t], wd = W1ea[3 * DH + t];
    float hs = 0.f;
#pragma unroll
    for (int e = 0; e < KNN; ++e) {
        float v = base + S[(size_t)ss[e] * DH + t]
                + sea[e * 4 + 0] * wa + sea[e * 4 + 1] * wb
                + sea[e * 4 + 2] * wc + sea[e * 4 + 3] * wd;
        hs += silu_f(v);
    }
    HS[(size_t)i * DH + t] = hs;
}

// ---------------------------------------------------------------- graph norm (one block per graph)
__global__ __launch_bounds__(256) void norm_kernel(
    const float* __restrict__ hn, float* __restrict__ h,
    const float* __restrict__ w, const float* __restrict__ b, const float* __restrict__ ms)
{
    int g = blockIdx.x, t = threadIdx.x;
    int d = t & 127, half = t >> 7;
    size_t base = (size_t)g * NPGR * DM;
    __shared__ float part[2][DM];
    __shared__ float meanv[DM], rstdv[DM], wv[DM], bv[DM], msv[DM];
    if (t < DM) { wv[t] = w[t]; bv[t] = b[t]; msv[t] = ms[t]; }
    float s = 0.f;
    for (int n = half * 512; n < half * 512 + 512; ++n) s += hn[base + (size_t)n * DM + d];
    part[half][d] = s;
    __syncthreads();
    if (t < DM) meanv[t] = (part[0][t] + part[1][t]) * (1.0f / NPGR);
    __syncthreads();
    float m = meanv[d] * msv[d];
    float s2 = 0.f;
    for (int n = half * 512; n < half * 512 + 512; ++n) {
        float o = hn[base + (size_t)n * DM + d] - m;
        s2 += o * o;
    }
    part[half][d] = s2;
    __syncthreads();
    if (t < DM) {
        float var = (part[0][t] + part[1][t]) * (1.0f / NPGR);
        rstdv[t] = 1.0f / sqrtf(var + 1e-5f);
    }
    __syncthreads();
    for (int idx = t; idx < NPGR * DM; idx += 256) {
        int dd = idx & 127;
        float o = hn[base + idx] - meanv[dd] * msv[dd];
        h[base + idx] = wv[dd] * o * rstdv[dd] + bv[dd];
    }
}

// ---------------------------------------------------------------- gate scalar per node, 8 nodes/block
__global__ __launch_bounds__(128) void gate_kernel(
    const float* __restrict__ h,
    const float* __restrict__ gW1, const float* __restrict__ gb1,
    const float* __restrict__ gW2, const float* __restrict__ gb2,
    float* __restrict__ gl)
{
    __shared__ float hh[8][DM];
    __shared__ float hid[8][DM];
    __shared__ float partial[2][8];
    int t = threadIdx.x;
    int nb = blockIdx.x * 8;
    for (int idx = t; idx < 8 * DM; idx += 128) hh[idx >> 7][idx & 127] = h[(size_t)nb * DM + idx];
    __syncthreads();
    float acc[8];
    float bb = gb1[t];
#pragma unroll
    for (int gi = 0; gi < 8; ++gi) acc[gi] = bb;
    for (int k = 0; k < DM; ++k) {
        float w = gW1[k * DM + t];
#pragma unroll
        for (int gi = 0; gi < 8; ++gi) acc[gi] += hh[gi][k] * w;
    }
#pragma unroll
    for (int gi = 0; gi < 8; ++gi) hid[gi][t] = tanhf(acc[gi]);
    __syncthreads();
    float w2 = gW2[t];
    int lane = t & 63, wv = t >> 6;
#pragma unroll
    for (int gi = 0; gi < 8; ++gi) {
        float v = hid[gi][t] * w2;
        for (int off = 32; off > 0; off >>= 1) v += __shfl_down(v, off, 64);
        if (lane == 0) partial[wv][gi] = v;
    }
    __syncthreads();
    if (t < 8) gl[nb + t] = partial[0][t] + partial[1][t] + gb2[0];
}

// ---------------------------------------------------------------- softmax pool + head (one block per graph)
__global__ __launch_bounds__(256) void pool_head_kernel(
    const float* __restrict__ h, const float* __restrict__ gl,
    const float* __restrict__ hW1, const float* __restrict__ hb1,
    const float* __restrict__ hW2, const float* __restrict__ hb2,
    float* __restrict__ outp)
{
    int g = blockIdx.x, t = threadIdx.x;
    __shared__ float red[4];
    __shared__ float el[NPGR];
    __shared__ float pl[DM];
    __shared__ float part[2][DM];
    __shared__ float hd[DM];
    size_t gbase = (size_t)g * NPGR;
    int lane = t & 63, wv = t >> 6;
    float mx = -3.4e38f;
    for (int n = t; n < NPGR; n += 256) mx = fmaxf(mx, gl[gbase + n]);
    for (int off = 32; off > 0; off >>= 1) mx = fmaxf(mx, __shfl_down(mx, off, 64));
    if (lane == 0) red[wv] = mx;
    __syncthreads();
    if (t == 0) red[0] = fmaxf(fmaxf(red[0], red[1]), fmaxf(red[2], red[3]));
    __syncthreads();
    float gmax = red[0];
    __syncthreads();
    float se = 0.f;
    for (int n = t; n < NPGR; n += 256) {
        float e = __expf(gl[gbase + n] - gmax);
        el[n] = e;
        se += e;
    }
    for (int off = 32; off > 0; off >>= 1) se += __shfl_down(se, off, 64);
    if (lane == 0) red[wv] = se;
    __syncthreads();
    float ssum = red[0] + red[1] + red[2] + red[3];
    int d = t & 127, half = t >> 7;
    float p = 0.f;
    for (int n = half * 512; n < half * 512 + 512; ++n) p += el[n] * h[(gbase + n) * DM + d];
    part[half][d] = p;
    __syncthreads();
    if (t < DM) pl[t] = (part[0][t] + part[1][t]) / ssum;
    __syncthreads();
    if (t < DM) {
        float a = hb1[t];
        for (int k = 0; k < DM; ++k) a += pl[k] * hW1[k * DM + t];
        hd[t] = silu_f(a);
    }
    __syncthreads();
    float vv = (t < DM) ? hd[t] * hW2[t] : 0.f;
    for (int off = 32; off > 0; off >>= 1) vv += __shfl_down(vv, off, 64);
    if (lane == 0) red[wv] = vv;
    __syncthreads();
    if (t == 0) outp[g] = red[0] + red[1] + red[2] + red[3] + hb2[0];
}

// ---------------------------------------------------------------- per-layer constants
__global__ __launch_bounds__(256) void precompute_kernel(
    const float* __restrict__ msgW2, const float* __restrict__ msgb2,
    const float* __restrict__ updW1, const float* __restrict__ updb1,
    float* __restrict__ W2U, float* __restrict__ bias2)
{
    int bid = blockIdx.x; int t = threadIdx.x;
    if (bid < NL * DH) {
        int l = bid / DH, k = bid % DH;
        const float* w2row = msgW2 + (size_t)l * DH * DM + (size_t)k * DM;
        const float* u1 = updW1 + (size_t)l * 2 * DM * DH;
        float acc = 0.f;
        for (int j = 0; j < DM; ++j) acc += w2row[j] * u1[(size_t)(DM + j) * DH + t];
        W2U[(size_t)l * DH * DH + (size_t)k * DH + t] = acc;
    } else {
        int l = bid - NL * DH;
        const float* u1 = updW1 + (size_t)l * 2 * DM * DH;
        const float* b2 = msgb2 + (size_t)l * DM;
        float acc = updb1[(size_t)l * DH + t];
        for (int j = 0; j < DM; ++j) acc += 12.0f * b2[j] * u1[(size_t)(DM + j) * DH + t];
        bias2[(size_t)l * DH + t] = acc;
    }
}

extern "C" void kernel_launch(void* const* d_in, const int* in_sizes, int n_in,
                              void* d_out, int out_size, void* d_ws, size_t ws_size,
                              hipStream_t stream) {
    const float* x     = (const float*)d_in[0];
    const float* inW1  = (const float*)d_in[2];
    const float* inb1  = (const float*)d_in[3];
    const float* inW2  = (const float*)d_in[4];
    const float* inb2  = (const float*)d_in[5];
    const float* msgW1 = (const float*)d_in[6];
    const float* msgb1 = (const float*)d_in[7];
    const float* msgW2 = (const float*)d_in[8];
    const float* msgb2 = (const float*)d_in[9];
    const float* updW1 = (const float*)d_in[10];
    const float* updb1 = (const float*)d_in[11];
    const float* updW2 = (const float*)d_in[12];
    const float* updb2 = (const float*)d_in[13];
    const float* nw    = (const float*)d_in[14];
    const float* nb    = (const float*)d_in[15];
    const float* nms   = (const float*)d_in[16];
    const float* gW1   = (const float*)d_in[17];
    const float* gb1   = (const float*)d_in[18];
    const float* gW2   = (const float*)d_in[19];
    const float* gb2   = (const float*)d_in[20];
    const float* hW1   = (const float*)d_in[21];
    const float* hb1   = (const float*)d_in[22];
    const float* hW2   = (const float*)d_in[23];
    const float* hb2   = (const float*)d_in[24];
    float* outp = (float*)d_out;

    float* ws   = (float*)d_ws;
    float* h    = ws;
    float* Cb   = h + (size_t)NPTS * DM;
    float* Sb   = Cb + (size_t)NPTS * DH;
    float* HSb  = Sb + (size_t)NPTS * DH;
    float* W2U  = HSb + (size_t)NPTS * DH;
    float* bias2 = W2U + (size_t)NL * DH * DH;
    float* glb  = bias2 + NL * DH;
    int* srcb   = (int*)(glb + NPTS);
    float* eab  = (float*)(srcb + EDG);

    hipLaunchKernelGGL(precompute_kernel, dim3(NL * DH + NL), dim3(DH), 0, stream,
                       msgW2, msgb2, updW1, updb1, W2U, bias2);
    hipLaunchKernelGGL(knn_kernel, dim3(NPTS / PPB), dim3(256), 0, stream, x, srcb, eab);
    hipLaunchKernelGGL(in_mlp_kernel, dim3(NPTS / 8), dim3(128), 0, stream,
                       x, inW1, inb1, inW2, inb2, h);

    for (int l = 0; l < NL; ++l) {
        const float* W1l = msgW1 + (size_t)l * (2 * DM + 4) * DH;
        hipLaunchKernelGGL(gemm_kernel, dim3(NPTS / BM, DH / BN), dim3(256), 0, stream,
            h, DM, DM, (const float*)nullptr, 0, 0,
            W1l, DH, (const float*)nullptr, 0,
            msgb1 + (size_t)l * DH, (const float*)nullptr, 0,
            Cb, DH, 0);
        hipLaunchKernelGGL(gemm_kernel, dim3(NPTS / BM, DH / BN), dim3(256), 0, stream,
            h, DM, DM, (const float*)nullptr, 0, 0,
            W1l + (size_t)DM * DH, DH, (const float*)nullptr, 0,
            (const float*)nullptr, (const float*)nullptr, 0,
            Sb, DH, 0);
        hipLaunchKernelGGL(edge_agg_kernel, dim3(NPTS), dim3(DH), 0, stream,
            Cb, Sb, srcb, eab, W1l + (size_t)2 * DM * DH, HSb);
        hipLaunchKernelGGL(gemm_kernel, dim3(NPTS / BM, DH / BN), dim3(256), 0, stream,
            h, DM, DM, HSb, DH, DH,
            updW1 + (size_t)l * 2 * DM * DH, DH, W2U + (size_t)l * DH * DH, DH,
            bias2 + (size_t)l * DH, (const float*)nullptr, 0,
            Cb, DH, 1);
        hipLaunchKernelGGL(gemm_kernel, dim3(NPTS / BM, DM / BN), dim3(256), 0, stream,
            Cb, DH, DH, (const float*)nullptr, 0, 0,
            updW2 + (size_t)l * DH * DM, DM, (const float*)nullptr, 0,
            updb2 + (size_t)l * DM, h, DM,
            Sb, DM, 0);
        hipLaunchKernelGGL(norm_kernel, dim3(BGR), dim3(256), 0, stream,
            Sb, h, nw + (size_t)l * DM, nb + (size_t)l * DM, nms + (size_t)l * DM);
    }

    hipLaunchKernelGGL(gate_kernel, dim3(NPTS / 8), dim3(128), 0, stream,
                       h, gW1, gb1, gW2, gb2, glb);
    hipLaunchKernelGGL(pool_head_kernel, dim3(BGR), dim3(256), 0, stream,
                       h, glb, hW1, hb1, hW2, hb2, outp);
}

// Round 3
// 627.133 us; speedup vs baseline: 2.1293x; 1.7490x over previous
//
#include <hip/hip_runtime.h>
#include <math.h>

#define NPTS 16384
#define BGR 16
#define NPGR 1024
#define KNN 12
#define DM 128
#define DH 256
#define NL 3
#define EDG (NPTS*KNN)

typedef unsigned short u16;
typedef unsigned int u32;
typedef __attribute__((ext_vector_type(8))) short short8;
typedef __attribute__((ext_vector_type(4))) float floatx4;

__device__ __forceinline__ float silu_f(float x) {
    return x / (1.0f + __expf(-x));
}
__device__ __forceinline__ u16 f2bf(float f) {
    union { float f; u32 u; } v; v.f = f;
    u32 r = v.u + 0x7fffu + ((v.u >> 16) & 1u);
    return (u16)(r >> 16);
}
__device__ __forceinline__ float bf2f(u16 b) {
    union { u32 u; float f; } v; v.u = ((u32)b) << 16;
    return v.f;
}

// ---------------------------------------------------------------- KNN + edge attrs
// 32 points/block, 8 threads/point (128 candidates each, private stable top-12),
// 8-way sorted merge with (d2, idx) tie-break == global stable insertion order.
#define KPPB 32
__global__ __launch_bounds__(256) void knn_kernel(const float* __restrict__ x,
                                                  int* __restrict__ srcb,
                                                  float* __restrict__ ea) {
#pragma clang fp contract(off)
    __shared__ float px[NPGR], py[NPGR], s0[NPGR];
    __shared__ float sdf[256 * 13];   // stride 13: conflict-free (13 coprime 32)
    __shared__ int   sif[256 * 13];
    __shared__ int   sel[KPPB][KNN];
    int t = threadIdx.x;
    int g   = blockIdx.x / (NPGR / KPPB);
    int blk = blockIdx.x % (NPGR / KPPB);
    int base = g * NPGR;
    for (int j = t; j < NPGR; j += 256) {
        const float* xp = x + (size_t)(base + j) * 3;
        s0[j] = xp[0]; px[j] = xp[1]; py[j] = xp[2];
    }
    __syncthreads();
    int r  = t & 7;
    int pt = t >> 3;
    int il = blk * KPPB + pt;
    float xi = px[il], yi = py[il];
    float nd[KNN]; int ni[KNN];
#pragma unroll
    for (int k = 0; k < KNN; ++k) { nd[k] = 3.4e38f; ni[k] = 0x7fffffff; }
    int j0 = r * 128;
    for (int jj = 0; jj < 128; ++jj) {
        int j = j0 + jj;
        if (j == il) continue;
        float dx = px[j] - xi;
        float dy = py[j] - yi;
        float dx2 = dx * dx;
        float dy2 = dy * dy;
        float d2 = dx2 + dy2;
        if (d2 < nd[KNN-1]) {
            float cd = d2; int ci = j;
#pragma unroll
            for (int k = 0; k < KNN; ++k) {
                bool sw = cd < nd[k];
                float tdv = sw ? nd[k] : cd;
                nd[k] = sw ? cd : nd[k];
                cd = tdv;
                int tiv = sw ? ni[k] : ci;
                ni[k] = sw ? ci : ni[k];
                ci = tiv;
            }
        }
    }
#pragma unroll
    for (int k = 0; k < KNN; ++k) { sdf[t * 13 + k] = nd[k]; sif[t * 13 + k] = ni[k]; }
    __syncthreads();
    if (r == 0) {
        int head[8] = {0,0,0,0,0,0,0,0};
#pragma unroll
        for (int k = 0; k < KNN; ++k) {
            float bd = 3.4e38f; int bi = 0x7fffffff; int bq = 0;
#pragma unroll
            for (int q = 0; q < 8; ++q) {
                int hq = head[q];
                float d = (hq < KNN) ? sdf[(pt * 8 + q) * 13 + hq] : 3.4e38f;
                int  ix = (hq < KNN) ? sif[(pt * 8 + q) * 13 + hq] : 0x7fffffff;
                if (d < bd || (d == bd && ix < bi)) { bd = d; bi = ix; bq = q; }
            }
            head[bq]++;
            sel[pt][k] = bi;
        }
    }
    __syncthreads();
    float x0i = s0[il];
    for (int k = r; k < KNN; k += 8) {
        int j = sel[pt][k];
        size_t e = (size_t)(base + il) * KNN + k;
        srcb[e] = base + j;
        float dpx = px[j] - xi, dpy = py[j] - yi;
        float a = dpx * dpx;
        float b = dpy * dpy;
        float dist = sqrtf(a + b + 1e-12f);
        float dsv = s0[j] - x0i;
        *(float4*)(ea + e * 4) = make_float4(dpx, dpy, dist, dsv);
    }
}

// ---------------------------------------------------------------- input MLP, 8 nodes/block
__global__ __launch_bounds__(128) void in_mlp_kernel(const float* __restrict__ x,
    const float* __restrict__ W1, const float* __restrict__ b1,
    const float* __restrict__ W2, const float* __restrict__ b2,
    float* __restrict__ h) {
    __shared__ float hid[8][DM];
    __shared__ float xl[8][3];
    int t = threadIdx.x;
    int nb = blockIdx.x * 8;
    if (t < 24) xl[t / 3][t % 3] = x[(size_t)nb * 3 + t];
    __syncthreads();
    float w0 = W1[t], w1 = W1[DM + t], w2 = W1[2 * DM + t], bb = b1[t];
#pragma unroll
    for (int gi = 0; gi < 8; ++gi) {
        float v = xl[gi][0] * w0 + xl[gi][1] * w1 + xl[gi][2] * w2 + bb;
        hid[gi][t] = silu_f(v);
    }
    __syncthreads();
    float acc[8];
    float b2v = b2[t];
#pragma unroll
    for (int gi = 0; gi < 8; ++gi) acc[gi] = b2v;
    for (int k = 0; k < DM; ++k) {
        float w = W2[k * DM + t];
#pragma unroll
        for (int gi = 0; gi < 8; ++gi) acc[gi] += hid[gi][k] * w;
    }
#pragma unroll
    for (int gi = 0; gi < 8; ++gi) h[(size_t)(nb + gi) * DM + t] = acc[gi];
}

// ---------------------------------------------------------------- split-bf16 MFMA GEMM
// out = act( [A0|A1] @ W^T + bias ) + resid, W pre-split bf16 hi/lo as [N][K].
// A fp32 split on the fly: A*B ~= Ah*Bh + Ah*Bl + Al*Bh (err ~1e-5 rel).
#define MBM 128
#define MBN 128
#define MBK 32
#define MLDA 40

__global__ __launch_bounds__(256) void mgemm_kernel(
    const float* __restrict__ A0, int k0, int lda0,
    const float* __restrict__ A1, int lda1,
    const u16* __restrict__ Wh, const u16* __restrict__ Wl, int K,
    const float* __restrict__ bias,
    const float* __restrict__ resid, int ldres,
    float* __restrict__ out, int ldout,
    int act)
{
    __shared__ __align__(16) u16 Ash[MBM * MLDA];
    __shared__ __align__(16) u16 Asl[MBM * MLDA];
    __shared__ __align__(16) u16 Bsh[MBN * MLDA];
    __shared__ __align__(16) u16 Bsl[MBN * MLDA];
    int t = threadIdx.x;
    int row0 = blockIdx.x * MBM, col0 = blockIdx.y * MBN;
    int lane = t & 63, w = t >> 6;
    int wm = (w >> 1) * 64, wn = (w & 1) * 64;
    int quad = lane >> 4, r15 = lane & 15;
    int srow = t >> 1, scol = (t & 1) * 16;

    floatx4 acc[4][4];
#pragma unroll
    for (int m = 0; m < 4; ++m)
#pragma unroll
        for (int n = 0; n < 4; ++n) acc[m][n] = (floatx4){0.f, 0.f, 0.f, 0.f};

    for (int kt = 0; kt < K; kt += MBK) {
        const float* Ap = (kt < k0)
            ? (A0 + (size_t)(row0 + srow) * lda0 + kt + scol)
            : (A1 + (size_t)(row0 + srow) * lda1 + (kt - k0) + scol);
        float4 a0 = ((const float4*)Ap)[0];
        float4 a1 = ((const float4*)Ap)[1];
        float4 a2 = ((const float4*)Ap)[2];
        float4 a3 = ((const float4*)Ap)[3];
        const u16* Bph = Wh + (size_t)(col0 + srow) * K + kt + scol;
        const u16* Bpl = Wl + (size_t)(col0 + srow) * K + kt + scol;
        uint4 bh0 = ((const uint4*)Bph)[0];
        uint4 bh1 = ((const uint4*)Bph)[1];
        uint4 bl0 = ((const uint4*)Bpl)[0];
        uint4 bl1 = ((const uint4*)Bpl)[1];
        __syncthreads();
        float av[16] = {a0.x,a0.y,a0.z,a0.w, a1.x,a1.y,a1.z,a1.w,
                        a2.x,a2.y,a2.z,a2.w, a3.x,a3.y,a3.z,a3.w};
        u32 uh[8], ul[8];
#pragma unroll
        for (int i = 0; i < 8; ++i) {
            u16 h0 = f2bf(av[2*i]);
            u16 h1 = f2bf(av[2*i+1]);
            u16 l0 = f2bf(av[2*i]   - bf2f(h0));
            u16 l1 = f2bf(av[2*i+1] - bf2f(h1));
            uh[i] = (u32)h0 | ((u32)h1 << 16);
            ul[i] = (u32)l0 | ((u32)l1 << 16);
        }
        uint4* adh = (uint4*)(Ash + srow * MLDA + scol);
        uint4* adl = (uint4*)(Asl + srow * MLDA + scol);
        adh[0] = make_uint4(uh[0],uh[1],uh[2],uh[3]);
        adh[1] = make_uint4(uh[4],uh[5],uh[6],uh[7]);
        adl[0] = make_uint4(ul[0],ul[1],ul[2],ul[3]);
        adl[1] = make_uint4(ul[4],ul[5],ul[6],ul[7]);
        uint4* bdh = (uint4*)(Bsh + srow * MLDA + scol);
        uint4* bdl = (uint4*)(Bsl + srow * MLDA + scol);
        bdh[0] = bh0; bdh[1] = bh1;
        bdl[0] = bl0; bdl[1] = bl1;
        __syncthreads();
        short8 ah[4], alo[4], bhf[4], blf[4];
#pragma unroll
        for (int m = 0; m < 4; ++m) {
            ah[m]  = *(const short8*)(Ash + (wm + m*16 + r15) * MLDA + quad*8);
            alo[m] = *(const short8*)(Asl + (wm + m*16 + r15) * MLDA + quad*8);
        }
#pragma unroll
        for (int n = 0; n < 4; ++n) {
            bhf[n] = *(const short8*)(Bsh + (wn + n*16 + r15) * MLDA + quad*8);
            blf[n] = *(const short8*)(Bsl + (wn + n*16 + r15) * MLDA + quad*8);
        }
#pragma unroll
        for (int m = 0; m < 4; ++m)
#pragma unroll
            for (int n = 0; n < 4; ++n) {
                acc[m][n] = __builtin_amdgcn_mfma_f32_16x16x32_bf16(ah[m],  bhf[n], acc[m][n], 0, 0, 0);
                acc[m][n] = __builtin_amdgcn_mfma_f32_16x16x32_bf16(ah[m],  blf[n], acc[m][n], 0, 0, 0);
                acc[m][n] = __builtin_amdgcn_mfma_f32_16x16x32_bf16(alo[m], bhf[n], acc[m][n], 0, 0, 0);
            }
    }
#pragma unroll
    for (int n = 0; n < 4; ++n) {
        int col = col0 + wn + n*16 + r15;
        float bv = bias ? bias[col] : 0.f;
#pragma unroll
        for (int m = 0; m < 4; ++m) {
#pragma unroll
            for (int reg = 0; reg < 4; ++reg) {
                int row = row0 + wm + m*16 + quad*4 + reg;
                float v = acc[m][n][reg] + bv;
                if (act == 1) v = silu_f(v);
                else if (act == 2) v = tanhf(v);
                if (resid) v += resid[(size_t)row * ldres + col];
                out[(size_t)row * ldout + col] = v;
            }
        }
    }
}

// ---------------------------------------------------------------- per-node edge aggregation
__global__ __launch_bounds__(256) void edge_agg_kernel(
    const float* __restrict__ C, const float* __restrict__ S,
    const int* __restrict__ srcb, const float* __restrict__ ea,
    const float* __restrict__ W1ea,
    float* __restrict__ HS)
{
    int i = blockIdx.x, t = threadIdx.x;
    __shared__ int ss[KNN];
    __shared__ float sea[KNN * 4];
    if (t < KNN) ss[t] = srcb[(size_t)i * KNN + t];
    if (t < KNN * 4) sea[t] = ea[(size_t)i * KNN * 4 + t];
    __syncthreads();
    float base = C[(size_t)i * DH + t];
    float wa = W1ea[t], wb = W1ea[DH + t], wc = W1ea[2 * DH + t], wd = W1ea[3 * DH + t];
    float hs = 0.f;
#pragma unroll
    for (int e = 0; e < KNN; ++e) {
        float v = base + S[(size_t)ss[e] * DH + t]
                + sea[e * 4 + 0] * wa + sea[e * 4 + 1] * wb
                + sea[e * 4 + 2] * wc + sea[e * 4 + 3] * wd;
        hs += silu_f(v);
    }
    HS[(size_t)i * DH + t] = hs;
}

// ---------------------------------------------------------------- two-phase graph norm
__global__ __launch_bounds__(256) void norm_part_kernel(const float* __restrict__ hn,
                                                        float* __restrict__ psum)
{
    int g = blockIdx.x, blk = blockIdx.y;
    int t = threadIdx.x, d = t & 127, half = t >> 7;
    size_t base = ((size_t)g * NPGR + (size_t)blk * 128 + half * 64) * DM;
    float s = 0.f, s2 = 0.f;
    for (int n = 0; n < 64; ++n) {
        float v = hn[base + (size_t)n * DM + d];
        s += v; s2 += v * v;
    }
    __shared__ float ps[2][DM], ps2[2][DM];
    ps[half][d] = s; ps2[half][d] = s2;
    __syncthreads();
    if (t < DM) {
        psum[(((size_t)g * 8 + blk) * 2 + 0) * DM + d] = ps[0][d] + ps[1][d];
        psum[(((size_t)g * 8 + blk) * 2 + 1) * DM + d] = ps2[0][d] + ps2[1][d];
    }
}

__global__ __launch_bounds__(256) void norm_apply_kernel(const float* __restrict__ hn,
    float* __restrict__ h, const float* __restrict__ psum,
    const float* __restrict__ w, const float* __restrict__ b, const float* __restrict__ ms)
{
    int g = blockIdx.x, blk = blockIdx.y, t = threadIdx.x;
    __shared__ float mmv[DM], rst[DM], wv[DM], bv[DM];
    if (t < DM) {
        float sum = 0.f, sq = 0.f;
        for (int q = 0; q < 8; ++q) {
            sum += psum[(((size_t)g * 8 + q) * 2 + 0) * DM + t];
            sq  += psum[(((size_t)g * 8 + q) * 2 + 1) * DM + t];
        }
        float mean = sum * (1.0f / NPGR);
        float mm = mean * ms[t];
        float var = sq * (1.0f / NPGR) - 2.f * mm * mean + mm * mm;
        mmv[t] = mm;
        rst[t] = 1.0f / sqrtf(var + 1e-5f);
        wv[t] = w[t]; bv[t] = b[t];
    }
    __syncthreads();
    size_t base = ((size_t)g * NPGR + (size_t)blk * 128) * DM;
    for (int i = t; i < 128 * DM; i += 256) {
        int dd = i & 127;
        float v = hn[base + i];
        h[base + i] = wv[dd] * (v - mmv[dd]) * rst[dd] + bv[dd];
    }
}

// ---------------------------------------------------------------- gate dot (1 node/wave)
__global__ __launch_bounds__(256) void gate_dot_kernel(const float* __restrict__ Gh,
    const float* __restrict__ gW2, const float* __restrict__ gb2,
    float* __restrict__ gl)
{
    int t = threadIdx.x, lane = t & 63, w = t >> 6;
    int node = blockIdx.x * 4 + w;
    const float* gp = Gh + (size_t)node * DM;
    float v = gp[lane] * gW2[lane] + gp[lane + 64] * gW2[lane + 64];
    for (int off = 32; off > 0; off >>= 1) v += __shfl_down(v, off, 64);
    if (lane == 0) gl[node] = v + gb2[0];
}

// ---------------------------------------------------------------- pooling (3 phases)
__global__ __launch_bounds__(256) void pool_stats_kernel(const float* __restrict__ gl,
                                                         float* __restrict__ gstat)
{
    int g = blockIdx.x, t = threadIdx.x, lane = t & 63, w = t >> 6;
    __shared__ float red[4];
    const float* gp = gl + (size_t)g * NPGR;
    float mx = -3.4e38f;
    for (int n = t; n < NPGR; n += 256) mx = fmaxf(mx, gp[n]);
    for (int off = 32; off > 0; off >>= 1) mx = fmaxf(mx, __shfl_down(mx, off, 64));
    if (lane == 0) red[w] = mx;
    __syncthreads();
    float gmax = fmaxf(fmaxf(red[0], red[1]), fmaxf(red[2], red[3]));
    __syncthreads();
    float se = 0.f;
    for (int n = t; n < NPGR; n += 256) se += __expf(gp[n] - gmax);
    for (int off = 32; off > 0; off >>= 1) se += __shfl_down(se, off, 64);
    if (lane == 0) red[w] = se;
    __syncthreads();
    if (t == 0) { gstat[g * 2] = gmax; gstat[g * 2 + 1] = red[0] + red[1] + red[2] + red[3]; }
}

__global__ __launch_bounds__(256) void pool_part_kernel(const float* __restrict__ h,
    const float* __restrict__ gl, const float* __restrict__ gstat,
    float* __restrict__ ppool)
{
    int g = blockIdx.x, blk = blockIdx.y;
    int t = threadIdx.x, d = t & 127, half = t >> 7;
    float gmax = gstat[g * 2];
    size_t nbase = (size_t)g * NPGR + (size_t)blk * 128 + half * 64;
    float p = 0.f;
    for (int n = 0; n < 64; ++n)
        p += __expf(gl[nbase + n] - gmax) * h[(nbase + n) * DM + d];
    __shared__ float ps[2][DM];
    ps[half][d] = p;
    __syncthreads();
    if (t < DM) ppool[((size_t)g * 8 + blk) * DM + d] = ps[0][d] + ps[1][d];
}

__global__ __launch_bounds__(128) void pool_head_kernel(const float* __restrict__ ppool,
    const float* __restrict__ gstat,
    const float* __restrict__ hW1, const float* __restrict__ hb1,
    const float* __restrict__ hW2, const float* __restrict__ hb2,
    float* __restrict__ outp)
{
    int g = blockIdx.x, t = threadIdx.x;
    __shared__ float pl[DM];
    __shared__ float red[2];
    float ssum = gstat[g * 2 + 1];
    float p = 0.f;
    for (int q = 0; q < 8; ++q) p += ppool[((size_t)g * 8 + q) * DM + t];
    pl[t] = p / ssum;
    __syncthreads();
    float a = hb1[t];
    for (int k = 0; k < DM; ++k) a += pl[k] * hW1[k * DM + t];
    a = silu_f(a);
    float vv = a * hW2[t];
    int lane = t & 63, w = t >> 6;
    for (int off = 32; off > 0; off >>= 1) vv += __shfl_down(vv, off, 64);
    if (lane == 0) red[w] = vv;
    __syncthreads();
    if (t == 0) outp[g] = red[0] + red[1] + hb2[0];
}

// ---------------------------------------------------------------- per-layer folded constants
__global__ __launch_bounds__(256) void precompute_kernel(
    const float* __restrict__ msgW2, const float* __restrict__ msgb2,
    const float* __restrict__ updW1, const float* __restrict__ updb1,
    float* __restrict__ W2U, float* __restrict__ bias2)
{
    int bid = blockIdx.x; int t = threadIdx.x;
    if (bid < NL * DH) {
        int l = bid / DH, k = bid % DH;
        const float* w2row = msgW2 + (size_t)l * DH * DM + (size_t)k * DM;
        const float* u1 = updW1 + (size_t)l * 2 * DM * DH;
        float acc = 0.f;
        for (int j = 0; j < DM; ++j) acc += w2row[j] * u1[(size_t)(DM + j) * DH + t];
        W2U[(size_t)l * DH * DH + (size_t)k * DH + t] = acc;
    } else {
        int l = bid - NL * DH;
        const float* u1 = updW1 + (size_t)l * 2 * DM * DH;
        const float* b2 = msgb2 + (size_t)l * DM;
        float acc = updb1[(size_t)l * DH + t];
        for (int j = 0; j < DM; ++j) acc += 12.0f * b2[j] * u1[(size_t)(DM + j) * DH + t];
        bias2[(size_t)l * DH + t] = acc;
    }
}

// ---------------------------------------------------------------- weight transpose + bf16 split
struct WJob { const float* src; u16* dh; u16* dl; int K, N, ldd, off; };
struct WJobs { WJob j[16]; };
__global__ __launch_bounds__(256) void wprep_kernel(WJobs jobs) {
    WJob jb = jobs.j[blockIdx.y];
    int n = blockIdx.x;
    if (n >= jb.N) return;
    for (int k = threadIdx.x; k < jb.K; k += 256) {
        float v = jb.src[(size_t)k * jb.N + n];
        u16 hi = f2bf(v);
        u16 lo = f2bf(v - bf2f(hi));
        jb.dh[(size_t)n * jb.ldd + jb.off + k] = hi;
        jb.dl[(size_t)n * jb.ldd + jb.off + k] = lo;
    }
}

extern "C" void kernel_launch(void* const* d_in, const int* in_sizes, int n_in,
                              void* d_out, int out_size, void* d_ws, size_t ws_size,
                              hipStream_t stream) {
    const float* x     = (const float*)d_in[0];
    const float* inW1  = (const float*)d_in[2];
    const float* inb1  = (const float*)d_in[3];
    const float* inW2  = (const float*)d_in[4];
    const float* inb2  = (const float*)d_in[5];
    const float* msgW1 = (const float*)d_in[6];
    const float* msgb1 = (const float*)d_in[7];
    const float* msgW2 = (const float*)d_in[8];
    const float* msgb2 = (const float*)d_in[9];
    const float* updW1 = (const float*)d_in[10];
    const float* updb1 = (const float*)d_in[11];
    const float* updW2 = (const float*)d_in[12];
    const float* updb2 = (const float*)d_in[13];
    const float* nw    = (const float*)d_in[14];
    const float* nb    = (const float*)d_in[15];
    const float* nms   = (const float*)d_in[16];
    const float* gW1   = (const float*)d_in[17];
    const float* gb1   = (const float*)d_in[18];
    const float* gW2   = (const float*)d_in[19];
    const float* gb2   = (const float*)d_in[20];
    const float* hW1   = (const float*)d_in[21];
    const float* hb1   = (const float*)d_in[22];
    const float* hW2   = (const float*)d_in[23];
    const float* hb2   = (const float*)d_in[24];
    float* outp = (float*)d_out;

    float* ws    = (float*)d_ws;
    float* h     = ws;                              // N*DM
    float* Cb    = h + (size_t)NPTS * DM;           // N*DH (also T, gate hidden)
    float* Sb    = Cb + (size_t)NPTS * DH;          // N*DH (also hn)
    float* HSb   = Sb + (size_t)NPTS * DH;          // N*DH
    float* W2U   = HSb + (size_t)NPTS * DH;         // 3*DH*DH
    float* bias2 = W2U + (size_t)NL * DH * DH;      // 3*DH
    float* glb   = bias2 + NL * DH;                 // N
    int*   srcb  = (int*)(glb + NPTS);              // E
    float* eab   = (float*)(srcb + EDG);            // E*4
    float* psum  = eab + (size_t)EDG * 4;           // 16*8*2*128
    float* gstat = psum + 16 * 8 * 2 * DM;          // 32
    float* ppool = gstat + 32;                      // 16*8*128
    u16* wsp = (u16*)(ppool + 16 * 8 * DM);
    u16* WCh = wsp;                 u16* WCl = WCh + (size_t)NL * DH * DM;
    u16* WSh = WCl + (size_t)NL * DH * DM;  u16* WSl = WSh + (size_t)NL * DH * DM;
    u16* WTh = WSl + (size_t)NL * DH * DM;  u16* WTl = WTh + (size_t)NL * DH * 384;
    u16* WUh = WTl + (size_t)NL * DH * 384; u16* WUl = WUh + (size_t)NL * DM * DH;
    u16* WGh = WUl + (size_t)NL * DM * DH;  u16* WGl = WGh + (size_t)DM * DM;

    hipLaunchKernelGGL(precompute_kernel, dim3(NL * DH + NL), dim3(DH), 0, stream,
                       msgW2, msgb2, updW1, updb1, W2U, bias2);

    WJobs jobs;
    int ji = 0;
    for (int l = 0; l < NL; ++l) {
        jobs.j[ji++] = WJob{ msgW1 + (size_t)l * 260 * DH,             WCh + (size_t)l * DH * DM, WCl + (size_t)l * DH * DM, 128, 256, 128, 0 };
        jobs.j[ji++] = WJob{ msgW1 + (size_t)l * 260 * DH + 128 * DH,  WSh + (size_t)l * DH * DM, WSl + (size_t)l * DH * DM, 128, 256, 128, 0 };
        jobs.j[ji++] = WJob{ updW1 + (size_t)l * 256 * DH,             WTh + (size_t)l * DH * 384, WTl + (size_t)l * DH * 384, 128, 256, 384, 0 };
        jobs.j[ji++] = WJob{ W2U   + (size_t)l * DH * DH,              WTh + (size_t)l * DH * 384, WTl + (size_t)l * DH * 384, 256, 256, 384, 128 };
        jobs.j[ji++] = WJob{ updW2 + (size_t)l * DH * DM,              WUh + (size_t)l * DM * DH, WUl + (size_t)l * DM * DH, 256, 128, 256, 0 };
    }
    jobs.j[ji++] = WJob{ gW1, WGh, WGl, 128, 128, 128, 0 };
    hipLaunchKernelGGL(wprep_kernel, dim3(256, 16), dim3(256), 0, stream, jobs);

    hipLaunchKernelGGL(knn_kernel, dim3(NPTS / KPPB), dim3(256), 0, stream, x, srcb, eab);
    hipLaunchKernelGGL(in_mlp_kernel, dim3(NPTS / 8), dim3(128), 0, stream,
                       x, inW1, inb1, inW2, inb2, h);

    for (int l = 0; l < NL; ++l) {
        const float* W1l = msgW1 + (size_t)l * 260 * DH;
        // C = h @ W1top + msg_b1
        hipLaunchKernelGGL(mgemm_kernel, dim3(NPTS / MBM, DH / MBN), dim3(256), 0, stream,
            h, DM, DM, (const float*)nullptr, 0,
            WCh + (size_t)l * DH * DM, WCl + (size_t)l * DH * DM, DM,
            msgb1 + (size_t)l * DH, (const float*)nullptr, 0, Cb, DH, 0);
        // S = h @ W1mid
        hipLaunchKernelGGL(mgemm_kernel, dim3(NPTS / MBM, DH / MBN), dim3(256), 0, stream,
            h, DM, DM, (const float*)nullptr, 0,
            WSh + (size_t)l * DH * DM, WSl + (size_t)l * DH * DM, DM,
            (const float*)nullptr, (const float*)nullptr, 0, Sb, DH, 0);
        // HS[i] = sum_e silu(C[i] + S[src] + ea.W1ea)
        hipLaunchKernelGGL(edge_agg_kernel, dim3(NPTS), dim3(DH), 0, stream,
            Cb, Sb, srcb, eab, W1l + (size_t)2 * DM * DH, HSb);
        // T = silu([h|HS] @ WT + bias2)
        hipLaunchKernelGGL(mgemm_kernel, dim3(NPTS / MBM, DH / MBN), dim3(256), 0, stream,
            h, DM, DM, HSb, DH,
            WTh + (size_t)l * DH * 384, WTl + (size_t)l * DH * 384, 384,
            bias2 + (size_t)l * DH, (const float*)nullptr, 0, Cb, DH, 1);
        // hn = h + T @ U2 + upd_b2
        hipLaunchKernelGGL(mgemm_kernel, dim3(NPTS / MBM, DM / MBN), dim3(256), 0, stream,
            Cb, DH, DH, (const float*)nullptr, 0,
            WUh + (size_t)l * DM * DH, WUl + (size_t)l * DM * DH, DH,
            updb2 + (size_t)l * DM, h, DM, Sb, DM, 0);
        // h = graph_norm(hn)
        hipLaunchKernelGGL(norm_part_kernel, dim3(BGR, 8), dim3(256), 0, stream, Sb, psum);
        hipLaunchKernelGGL(norm_apply_kernel, dim3(BGR, 8), dim3(256), 0, stream,
            Sb, h, psum, nw + (size_t)l * DM, nb + (size_t)l * DM, nms + (size_t)l * DM);
    }

    // gate hidden = tanh(h @ gW1 + gb1) via MFMA, then dot with gW2
    hipLaunchKernelGGL(mgemm_kernel, dim3(NPTS / MBM, DM / MBN), dim3(256), 0, stream,
        h, DM, DM, (const float*)nullptr, 0,
        WGh, WGl, DM, gb1, (const float*)nullptr, 0, Cb, DM, 2);
    hipLaunchKernelGGL(gate_dot_kernel, dim3(NPTS / 4), dim3(256), 0, stream,
        Cb, gW2, gb2, glb);

    hipLaunchKernelGGL(pool_stats_kernel, dim3(BGR), dim3(256), 0, stream, glb, gstat);
    hipLaunchKernelGGL(pool_part_kernel, dim3(BGR, 8), dim3(256), 0, stream, h, glb, gstat, ppool);
    hipLaunchKernelGGL(pool_head_kernel, dim3(BGR), dim3(128), 0, stream,
        ppool, gstat, hW1, hb1, hW2, hb2, outp);
}

// Round 4
// 541.687 us; speedup vs baseline: 2.4652x; 1.1577x over previous
//
#include <hip/hip_runtime.h>
#include <math.h>

#define NPTS 16384
#define BGR 16
#define NPGR 1024
#define KNN 12
#define DM 128
#define DH 256
#define NL 3
#define EDG (NPTS*KNN)

typedef unsigned short u16;
typedef unsigned int u32;
typedef __attribute__((ext_vector_type(8))) short short8;
typedef __attribute__((ext_vector_type(4))) float floatx4;

__device__ __forceinline__ float silu_f(float x) {
    return x / (1.0f + __expf(-x));
}
__device__ __forceinline__ u16 f2bf(float f) {
    union { float f; u32 u; } v; v.f = f;
    u32 r = v.u + 0x7fffu + ((v.u >> 16) & 1u);
    return (u16)(r >> 16);
}
__device__ __forceinline__ float bf2f(u16 b) {
    union { u32 u; float f; } v; v.u = ((u32)b) << 16;
    return v.f;
}

// ---------------------------------------------------------------- KNN + edge attrs
// 16 points/block, 16 threads/point (64 candidates each, private stable top-12),
// 16-way sorted merge with (d2, idx) tie-break == global stable insertion order.
// Point-region stride 209 (odd, ==17 mod 32) -> conflict-free merge reads.
#define KPPB 16
#define PSTR 209
__global__ __launch_bounds__(256) void knn_kernel(const float* __restrict__ x,
                                                  int* __restrict__ srcb,
                                                  float* __restrict__ ea) {
#pragma clang fp contract(off)
    __shared__ float px[NPGR], py[NPGR], s0[NPGR];
    __shared__ float sdf[KPPB * PSTR];
    __shared__ int   sif[KPPB * PSTR];
    __shared__ int   sel[KPPB][KNN];
    int t = threadIdx.x;
    int g   = blockIdx.x / (NPGR / KPPB);
    int blk = blockIdx.x % (NPGR / KPPB);
    int base = g * NPGR;
    for (int j = t; j < NPGR; j += 256) {
        const float* xp = x + (size_t)(base + j) * 3;
        s0[j] = xp[0]; px[j] = xp[1]; py[j] = xp[2];
    }
    __syncthreads();
    int r  = t & 15;
    int pt = t >> 4;
    int il = blk * KPPB + pt;
    float xi = px[il], yi = py[il];
    float nd[KNN]; int ni[KNN];
#pragma unroll
    for (int k = 0; k < KNN; ++k) { nd[k] = 3.4e38f; ni[k] = 0x7fffffff; }
    int j0 = r * 64;
    for (int jj = 0; jj < 64; ++jj) {
        int j = j0 + jj;
        if (j == il) continue;
        float dx = px[j] - xi;
        float dy = py[j] - yi;
        float dx2 = dx * dx;
        float dy2 = dy * dy;
        float d2 = dx2 + dy2;
        if (d2 < nd[KNN-1]) {
            float cd = d2; int ci = j;
#pragma unroll
            for (int k = 0; k < KNN; ++k) {
                bool sw = cd < nd[k];
                float tdv = sw ? nd[k] : cd;
                nd[k] = sw ? cd : nd[k];
                cd = tdv;
                int tiv = sw ? ni[k] : ci;
                ni[k] = sw ? ci : ni[k];
                ci = tiv;
            }
        }
    }
#pragma unroll
    for (int k = 0; k < KNN; ++k) {
        sdf[pt * PSTR + r * 13 + k] = nd[k];
        sif[pt * PSTR + r * 13 + k] = ni[k];
    }
    __syncthreads();
    if (r == 0) {
        int head[16];
#pragma unroll
        for (int q = 0; q < 16; ++q) head[q] = 0;
#pragma unroll
        for (int k = 0; k < KNN; ++k) {
            float bd = 3.4e38f; int bi = 0x7fffffff; int bq = 0;
#pragma unroll
            for (int q = 0; q < 16; ++q) {
                int hq = head[q];
                float d = (hq < KNN) ? sdf[pt * PSTR + q * 13 + hq] : 3.4e38f;
                int  ix = (hq < KNN) ? sif[pt * PSTR + q * 13 + hq] : 0x7fffffff;
                if (d < bd || (d == bd && ix < bi)) { bd = d; bi = ix; bq = q; }
            }
            head[bq]++;
            sel[pt][k] = bi;
        }
    }
    __syncthreads();
    if (r < KNN) {
        int k = r;
        int j = sel[pt][k];
        size_t e = (size_t)(base + il) * KNN + k;
        srcb[e] = base + j;
        float x0i = s0[il];
        float dpx = px[j] - xi, dpy = py[j] - yi;
        float a = dpx * dpx;
        float b = dpy * dpy;
        float dist = sqrtf(a + b + 1e-12f);
        float dsv = s0[j] - x0i;
        *(float4*)(ea + e * 4) = make_float4(dpx, dpy, dist, dsv);
    }
}

// ---------------------------------------------------------------- input MLP, 8 nodes/block
__global__ __launch_bounds__(128) void in_mlp_kernel(const float* __restrict__ x,
    const float* __restrict__ W1, const float* __restrict__ b1,
    const float* __restrict__ W2, const float* __restrict__ b2,
    float* __restrict__ h) {
    __shared__ float hid[8][DM];
    __shared__ float xl[8][3];
    int t = threadIdx.x;
    int nb = blockIdx.x * 8;
    if (t < 24) xl[t / 3][t % 3] = x[(size_t)nb * 3 + t];
    __syncthreads();
    float w0 = W1[t], w1 = W1[DM + t], w2 = W1[2 * DM + t], bb = b1[t];
#pragma unroll
    for (int gi = 0; gi < 8; ++gi) {
        float v = xl[gi][0] * w0 + xl[gi][1] * w1 + xl[gi][2] * w2 + bb;
        hid[gi][t] = silu_f(v);
    }
    __syncthreads();
    float acc[8];
    float b2v = b2[t];
#pragma unroll
    for (int gi = 0; gi < 8; ++gi) acc[gi] = b2v;
    for (int k = 0; k < DM; ++k) {
        float w = W2[k * DM + t];
#pragma unroll
        for (int gi = 0; gi < 8; ++gi) acc[gi] += hid[gi][k] * w;
    }
#pragma unroll
    for (int gi = 0; gi < 8; ++gi) h[(size_t)(nb + gi) * DM + t] = acc[gi];
}

// ---------------------------------------------------------------- split-bf16 MFMA GEMM
// 64x128 block tile, 4 waves (2x2), wave tile 32x64. W pre-split bf16 hi/lo [N][K].
// A fp32 split on the fly: A*B ~= Ah*Bh + Ah*Bl + Al*Bh.
#define MBM 64
#define MBN 128
#define MBK 32
#define MLDA 40

__global__ __launch_bounds__(256) void mgemm_kernel(
    const float* __restrict__ A0, int k0, int lda0,
    const float* __restrict__ A1, int lda1,
    const u16* __restrict__ Wh, const u16* __restrict__ Wl, int K,
    const float* __restrict__ bias, int biasN,
    const float* __restrict__ resid, int ldres,
    float* __restrict__ out, int ldout,
    int act)
{
    __shared__ __align__(16) u16 Ash[MBM * MLDA];
    __shared__ __align__(16) u16 Asl[MBM * MLDA];
    __shared__ __align__(16) u16 Bsh[MBN * MLDA];
    __shared__ __align__(16) u16 Bsl[MBN * MLDA];
    int t = threadIdx.x;
    int row0 = blockIdx.x * MBM, col0 = blockIdx.y * MBN;
    int lane = t & 63, w = t >> 6;
    int wm = (w >> 1) * 32, wn = (w & 1) * 64;
    int quad = lane >> 4, r15 = lane & 15;
    int arow = t >> 2, acol = (t & 3) * 8;   // A staging: 64 rows x 32 cols, 8 f32/thread
    int brow = t >> 1, bcol = (t & 1) * 16;  // B staging: 128 rows x 32 cols, 16 u16/thread

    floatx4 acc[2][4];
#pragma unroll
    for (int m = 0; m < 2; ++m)
#pragma unroll
        for (int n = 0; n < 4; ++n) acc[m][n] = (floatx4){0.f, 0.f, 0.f, 0.f};

    for (int kt = 0; kt < K; kt += MBK) {
        const float* Ap = (kt < k0)
            ? (A0 + (size_t)(row0 + arow) * lda0 + kt + acol)
            : (A1 + (size_t)(row0 + arow) * lda1 + (kt - k0) + acol);
        float4 a0 = ((const float4*)Ap)[0];
        float4 a1 = ((const float4*)Ap)[1];
        const u16* Bph = Wh + (size_t)(col0 + brow) * K + kt + bcol;
        const u16* Bpl = Wl + (size_t)(col0 + brow) * K + kt + bcol;
        uint4 bh0 = ((const uint4*)Bph)[0];
        uint4 bh1 = ((const uint4*)Bph)[1];
        uint4 bl0 = ((const uint4*)Bpl)[0];
        uint4 bl1 = ((const uint4*)Bpl)[1];
        __syncthreads();
        float av[8] = {a0.x,a0.y,a0.z,a0.w, a1.x,a1.y,a1.z,a1.w};
        u32 uh[4], ul[4];
#pragma unroll
        for (int i = 0; i < 4; ++i) {
            u16 h0 = f2bf(av[2*i]);
            u16 h1 = f2bf(av[2*i+1]);
            u16 l0 = f2bf(av[2*i]   - bf2f(h0));
            u16 l1 = f2bf(av[2*i+1] - bf2f(h1));
            uh[i] = (u32)h0 | ((u32)h1 << 16);
            ul[i] = (u32)l0 | ((u32)l1 << 16);
        }
        *(uint4*)(Ash + arow * MLDA + acol) = make_uint4(uh[0],uh[1],uh[2],uh[3]);
        *(uint4*)(Asl + arow * MLDA + acol) = make_uint4(ul[0],ul[1],ul[2],ul[3]);
        uint4* bdh = (uint4*)(Bsh + brow * MLDA + bcol);
        uint4* bdl = (uint4*)(Bsl + brow * MLDA + bcol);
        bdh[0] = bh0; bdh[1] = bh1;
        bdl[0] = bl0; bdl[1] = bl1;
        __syncthreads();
        short8 ah[2], alo[2], bhf[4], blf[4];
#pragma unroll
        for (int m = 0; m < 2; ++m) {
            ah[m]  = *(const short8*)(Ash + (wm + m*16 + r15) * MLDA + quad*8);
            alo[m] = *(const short8*)(Asl + (wm + m*16 + r15) * MLDA + quad*8);
        }
#pragma unroll
        for (int n = 0; n < 4; ++n) {
            bhf[n] = *(const short8*)(Bsh + (wn + n*16 + r15) * MLDA + quad*8);
            blf[n] = *(const short8*)(Bsl + (wn + n*16 + r15) * MLDA + quad*8);
        }
#pragma unroll
        for (int m = 0; m < 2; ++m)
#pragma unroll
            for (int n = 0; n < 4; ++n) {
                acc[m][n] = __builtin_amdgcn_mfma_f32_16x16x32_bf16(ah[m],  bhf[n], acc[m][n], 0, 0, 0);
                acc[m][n] = __builtin_amdgcn_mfma_f32_16x16x32_bf16(ah[m],  blf[n], acc[m][n], 0, 0, 0);
                acc[m][n] = __builtin_amdgcn_mfma_f32_16x16x32_bf16(alo[m], bhf[n], acc[m][n], 0, 0, 0);
            }
    }
#pragma unroll
    for (int n = 0; n < 4; ++n) {
        int col = col0 + wn + n*16 + r15;
        float bv = (bias && col < biasN) ? bias[col] : 0.f;
#pragma unroll
        for (int m = 0; m < 2; ++m) {
#pragma unroll
            for (int reg = 0; reg < 4; ++reg) {
                int row = row0 + wm + m*16 + quad*4 + reg;
                float v = acc[m][n][reg] + bv;
                if (act == 1) v = silu_f(v);
                else if (act == 2) v = tanhf(v);
                if (resid) v += resid[(size_t)row * ldres + col];
                out[(size_t)row * ldout + col] = v;
            }
        }
    }
}

// ---------------------------------------------------------------- per-node edge aggregation
// CS layout: [i][0:256] = C row, [i][256:512] = S row (ld 512).
__global__ __launch_bounds__(256) void edge_agg_kernel(
    const float* __restrict__ CS,
    const int* __restrict__ srcb, const float* __restrict__ ea,
    const float* __restrict__ W1ea,
    float* __restrict__ HS)
{
    int i = blockIdx.x, t = threadIdx.x;
    __shared__ int ss[KNN];
    __shared__ float sea[KNN * 4];
    if (t < KNN) ss[t] = srcb[(size_t)i * KNN + t];
    if (t < KNN * 4) sea[t] = ea[(size_t)i * KNN * 4 + t];
    __syncthreads();
    float base = CS[(size_t)i * 512 + t];
    float wa = W1ea[t], wb = W1ea[DH + t], wc = W1ea[2 * DH + t], wd = W1ea[3 * DH + t];
    float hs = 0.f;
#pragma unroll
    for (int e = 0; e < KNN; ++e) {
        float v = base + CS[(size_t)ss[e] * 512 + 256 + t]
                + sea[e * 4 + 0] * wa + sea[e * 4 + 1] * wb
                + sea[e * 4 + 2] * wc + sea[e * 4 + 3] * wd;
        hs += silu_f(v);
    }
    HS[(size_t)i * DH + t] = hs;
}

// ---------------------------------------------------------------- two-phase graph norm
__global__ __launch_bounds__(256) void norm_part_kernel(const float* __restrict__ hn,
                                                        float* __restrict__ psum)
{
    int g = blockIdx.x, blk = blockIdx.y;
    int t = threadIdx.x, d = t & 127, half = t >> 7;
    size_t base = ((size_t)g * NPGR + (size_t)blk * 128 + half * 64) * DM;
    float s = 0.f, s2 = 0.f;
    for (int n = 0; n < 64; ++n) {
        float v = hn[base + (size_t)n * DM + d];
        s += v; s2 += v * v;
    }
    __shared__ float ps[2][DM], ps2[2][DM];
    ps[half][d] = s; ps2[half][d] = s2;
    __syncthreads();
    if (t < DM) {
        psum[(((size_t)g * 8 + blk) * 2 + 0) * DM + d] = ps[0][d] + ps[1][d];
        psum[(((size_t)g * 8 + blk) * 2 + 1) * DM + d] = ps2[0][d] + ps2[1][d];
    }
}

__global__ __launch_bounds__(256) void norm_apply_kernel(const float* __restrict__ hn,
    float* __restrict__ h, const float* __restrict__ psum,
    const float* __restrict__ w, const float* __restrict__ b, const float* __restrict__ ms)
{
    int g = blockIdx.x, blk = blockIdx.y, t = threadIdx.x;
    __shared__ float mmv[DM], rst[DM], wv[DM], bv[DM];
    if (t < DM) {
        float sum = 0.f, sq = 0.f;
        for (int q = 0; q < 8; ++q) {
            sum += psum[(((size_t)g * 8 + q) * 2 + 0) * DM + t];
            sq  += psum[(((size_t)g * 8 + q) * 2 + 1) * DM + t];
        }
        float mean = sum * (1.0f / NPGR);
        float mm = mean * ms[t];
        float var = sq * (1.0f / NPGR) - 2.f * mm * mean + mm * mm;
        mmv[t] = mm;
        rst[t] = 1.0f / sqrtf(var + 1e-5f);
        wv[t] = w[t]; bv[t] = b[t];
    }
    __syncthreads();
    size_t base = ((size_t)g * NPGR + (size_t)blk * 128) * DM;
    for (int i = t; i < 128 * DM; i += 256) {
        int dd = i & 127;
        float v = hn[base + i];
        h[base + i] = wv[dd] * (v - mmv[dd]) * rst[dd] + bv[dd];
    }
}

// ---------------------------------------------------------------- gate dot (1 node/wave)
__global__ __launch_bounds__(256) void gate_dot_kernel(const float* __restrict__ Gh,
    const float* __restrict__ gW2, const float* __restrict__ gb2,
    float* __restrict__ gl)
{
    int t = threadIdx.x, lane = t & 63, w = t >> 6;
    int node = blockIdx.x * 4 + w;
    const float* gp = Gh + (size_t)node * DM;
    float v = gp[lane] * gW2[lane] + gp[lane + 64] * gW2[lane + 64];
    for (int off = 32; off > 0; off >>= 1) v += __shfl_down(v, off, 64);
    if (lane == 0) gl[node] = v + gb2[0];
}

// ---------------------------------------------------------------- pooling (3 phases)
__global__ __launch_bounds__(256) void pool_stats_kernel(const float* __restrict__ gl,
                                                         float* __restrict__ gstat)
{
    int g = blockIdx.x, t = threadIdx.x, lane = t & 63, w = t >> 6;
    __shared__ float red[4];
    const float* gp = gl + (size_t)g * NPGR;
    float mx = -3.4e38f;
    for (int n = t; n < NPGR; n += 256) mx = fmaxf(mx, gp[n]);
    for (int off = 32; off > 0; off >>= 1) mx = fmaxf(mx, __shfl_down(mx, off, 64));
    if (lane == 0) red[w] = mx;
    __syncthreads();
    float gmax = fmaxf(fmaxf(red[0], red[1]), fmaxf(red[2], red[3]));
    __syncthreads();
    float se = 0.f;
    for (int n = t; n < NPGR; n += 256) se += __expf(gp[n] - gmax);
    for (int off = 32; off > 0; off >>= 1) se += __shfl_down(se, off, 64);
    if (lane == 0) red[w] = se;
    __syncthreads();
    if (t == 0) { gstat[g * 2] = gmax; gstat[g * 2 + 1] = red[0] + red[1] + red[2] + red[3]; }
}

__global__ __launch_bounds__(256) void pool_part_kernel(const float* __restrict__ h,
    const float* __restrict__ gl, const float* __restrict__ gstat,
    float* __restrict__ ppool)
{
    int g = blockIdx.x, blk = blockIdx.y;
    int t = threadIdx.x, d = t & 127, half = t >> 7;
    float gmax = gstat[g * 2];
    size_t nbase = (size_t)g * NPGR + (size_t)blk * 128 + half * 64;
    float p = 0.f;
    for (int n = 0; n < 64; ++n)
        p += __expf(gl[nbase + n] - gmax) * h[(nbase + n) * DM + d];
    __shared__ float ps[2][DM];
    ps[half][d] = p;
    __syncthreads();
    if (t < DM) ppool[((size_t)g * 8 + blk) * DM + d] = ps[0][d] + ps[1][d];
}

__global__ __launch_bounds__(128) void pool_head_kernel(const float* __restrict__ ppool,
    const float* __restrict__ gstat,
    const float* __restrict__ hW1, const float* __restrict__ hb1,
    const float* __restrict__ hW2, const float* __restrict__ hb2,
    float* __restrict__ outp)
{
    int g = blockIdx.x, t = threadIdx.x;
    __shared__ float pl[DM];
    __shared__ float red[2];
    float ssum = gstat[g * 2 + 1];
    float p = 0.f;
    for (int q = 0; q < 8; ++q) p += ppool[((size_t)g * 8 + q) * DM + t];
    pl[t] = p / ssum;
    __syncthreads();
    float a = hb1[t];
    for (int k = 0; k < DM; ++k) a += pl[k] * hW1[k * DM + t];
    a = silu_f(a);
    float vv = a * hW2[t];
    int lane = t & 63, w = t >> 6;
    for (int off = 32; off > 0; off >>= 1) vv += __shfl_down(vv, off, 64);
    if (lane == 0) red[w] = vv;
    __syncthreads();
    if (t == 0) outp[g] = red[0] + red[1] + hb2[0];
}

// ---------------------------------------------------------------- per-layer folded constants
__global__ __launch_bounds__(256) void precompute_kernel(
    const float* __restrict__ msgW2, const float* __restrict__ msgb2,
    const float* __restrict__ updW1, const float* __restrict__ updb1,
    float* __restrict__ W2U, float* __restrict__ bias2)
{
    int bid = blockIdx.x; int t = threadIdx.x;
    if (bid < NL * DH) {
        int l = bid / DH, k = bid % DH;
        const float* w2row = msgW2 + (size_t)l * DH * DM + (size_t)k * DM;
        const float* u1 = updW1 + (size_t)l * 2 * DM * DH;
        float acc = 0.f;
        for (int j = 0; j < DM; ++j) acc += w2row[j] * u1[(size_t)(DM + j) * DH + t];
        W2U[(size_t)l * DH * DH + (size_t)k * DH + t] = acc;
    } else {
        int l = bid - NL * DH;
        const float* u1 = updW1 + (size_t)l * 2 * DM * DH;
        const float* b2 = msgb2 + (size_t)l * DM;
        float acc = updb1[(size_t)l * DH + t];
        for (int j = 0; j < DM; ++j) acc += 12.0f * b2[j] * u1[(size_t)(DM + j) * DH + t];
        bias2[(size_t)l * DH + t] = acc;
    }
}

// ---------------------------------------------------------------- weight transpose + bf16 split
struct WJob { const float* src; u16* dh; u16* dl; int K, N, ldd, off; };
struct WJobs { WJob j[16]; };
__global__ __launch_bounds__(256) void wprep_kernel(WJobs jobs) {
    WJob jb = jobs.j[blockIdx.y];
    int n = blockIdx.x;
    if (n >= jb.N) return;
    for (int k = threadIdx.x; k < jb.K; k += 256) {
        float v = jb.src[(size_t)k * jb.N + n];
        u16 hi = f2bf(v);
        u16 lo = f2bf(v - bf2f(hi));
        jb.dh[(size_t)n * jb.ldd + jb.off + k] = hi;
        jb.dl[(size_t)n * jb.ldd + jb.off + k] = lo;
    }
}

extern "C" void kernel_launch(void* const* d_in, const int* in_sizes, int n_in,
                              void* d_out, int out_size, void* d_ws, size_t ws_size,
                              hipStream_t stream) {
    const float* x     = (const float*)d_in[0];
    const float* inW1  = (const float*)d_in[2];
    const float* inb1  = (const float*)d_in[3];
    const float* inW2  = (const float*)d_in[4];
    const float* inb2  = (const float*)d_in[5];
    const float* msgW1 = (const float*)d_in[6];
    const float* msgb1 = (const float*)d_in[7];
    const float* msgW2 = (const float*)d_in[8];
    const float* msgb2 = (const float*)d_in[9];
    const float* updW1 = (const float*)d_in[10];
    const float* updb1 = (const float*)d_in[11];
    const float* updW2 = (const float*)d_in[12];
    const float* updb2 = (const float*)d_in[13];
    const float* nw    = (const float*)d_in[14];
    const float* nb    = (const float*)d_in[15];
    const float* nms   = (const float*)d_in[16];
    const float* gW1   = (const float*)d_in[17];
    const float* gb1   = (const float*)d_in[18];
    const float* gW2   = (const float*)d_in[19];
    const float* gb2   = (const float*)d_in[20];
    const float* hW1   = (const float*)d_in[21];
    const float* hb1   = (const float*)d_in[22];
    const float* hW2   = (const float*)d_in[23];
    const float* hb2   = (const float*)d_in[24];
    float* outp = (float*)d_out;

    float* ws    = (float*)d_ws;
    float* h     = ws;                              // N*DM
    float* CSb   = h + (size_t)NPTS * DM;           // N*512: [C|S]; also T (ld 512), gate hidden (ld 128)
    float* HSb   = CSb + (size_t)NPTS * 512;        // N*DH; also hn
    float* W2U   = HSb + (size_t)NPTS * DH;         // 3*DH*DH
    float* bias2 = W2U + (size_t)NL * DH * DH;      // 3*DH
    float* glb   = bias2 + NL * DH;                 // N
    int*   srcb  = (int*)(glb + NPTS);              // E
    float* eab   = (float*)(srcb + EDG);            // E*4
    float* psum  = eab + (size_t)EDG * 4;           // 16*8*2*128
    float* gstat = psum + 16 * 8 * 2 * DM;          // 32
    float* ppool = gstat + 32;                      // 16*8*128
    u16* wsp = (u16*)(ppool + 16 * 8 * DM);
    u16* WCSh = wsp;                                 u16* WCSl = WCSh + (size_t)NL * 512 * DM;
    u16* WTh = WCSl + (size_t)NL * 512 * DM;         u16* WTl = WTh + (size_t)NL * DH * 384;
    u16* WUh = WTl + (size_t)NL * DH * 384;          u16* WUl = WUh + (size_t)NL * DM * DH;
    u16* WGh = WUl + (size_t)NL * DM * DH;           u16* WGl = WGh + (size_t)DM * DM;

    hipLaunchKernelGGL(precompute_kernel, dim3(NL * DH + NL), dim3(DH), 0, stream,
                       msgW2, msgb2, updW1, updb1, W2U, bias2);

    WJobs jobs;
    int ji = 0;
    for (int l = 0; l < NL; ++l) {
        // CS weights: rows 0..255 of fused N=512 -> C (msgW1 top), 256..511 -> S (msgW1 mid)
        jobs.j[ji++] = WJob{ msgW1 + (size_t)l * 260 * DH,            WCSh + (size_t)l * 512 * DM,            WCSl + (size_t)l * 512 * DM,            128, 256, 128, 0 };
        jobs.j[ji++] = WJob{ msgW1 + (size_t)l * 260 * DH + 128 * DH, WCSh + (size_t)l * 512 * DM + 256 * DM, WCSl + (size_t)l * 512 * DM + 256 * DM, 128, 256, 128, 0 };
        jobs.j[ji++] = WJob{ updW1 + (size_t)l * 256 * DH,            WTh + (size_t)l * DH * 384, WTl + (size_t)l * DH * 384, 128, 256, 384, 0 };
        jobs.j[ji++] = WJob{ W2U   + (size_t)l * DH * DH,             WTh + (size_t)l * DH * 384, WTl + (size_t)l * DH * 384, 256, 256, 384, 128 };
        jobs.j[ji++] = WJob{ updW2 + (size_t)l * DH * DM,             WUh + (size_t)l * DM * DH, WUl + (size_t)l * DM * DH, 256, 128, 256, 0 };
    }
    jobs.j[ji++] = WJob{ gW1, WGh, WGl, 128, 128, 128, 0 };
    hipLaunchKernelGGL(wprep_kernel, dim3(256, 16), dim3(256), 0, stream, jobs);

    hipLaunchKernelGGL(knn_kernel, dim3(NPTS / KPPB), dim3(256), 0, stream, x, srcb, eab);
    hipLaunchKernelGGL(in_mlp_kernel, dim3(NPTS / 8), dim3(128), 0, stream,
                       x, inW1, inb1, inW2, inb2, h);

    for (int l = 0; l < NL; ++l) {
        const float* W1l = msgW1 + (size_t)l * 260 * DH;
        // [C|S] = h @ [W1top|W1mid] + [msg_b1|0]   (N=512, 1024 blocks)
        hipLaunchKernelGGL(mgemm_kernel, dim3(NPTS / MBM, 512 / MBN), dim3(256), 0, stream,
            h, DM, DM, (const float*)nullptr, 0,
            WCSh + (size_t)l * 512 * DM, WCSl + (size_t)l * 512 * DM, DM,
            msgb1 + (size_t)l * DH, 256, (const float*)nullptr, 0, CSb, 512, 0);
        // HS[i] = sum_e silu(C[i] + S[src] + ea.W1ea)
        hipLaunchKernelGGL(edge_agg_kernel, dim3(NPTS), dim3(DH), 0, stream,
            CSb, srcb, eab, W1l + (size_t)2 * DM * DH, HSb);
        // T = silu([h|HS] @ WT + bias2)  -> into CSb cols 0..255 (ld 512)
        hipLaunchKernelGGL(mgemm_kernel, dim3(NPTS / MBM, DH / MBN), dim3(256), 0, stream,
            h, DM, DM, HSb, DH,
            WTh + (size_t)l * DH * 384, WTl + (size_t)l * DH * 384, 384,
            bias2 + (size_t)l * DH, DH, (const float*)nullptr, 0, CSb, 512, 1);
        // hn = h + T @ U2 + upd_b2  -> into HSb (ld 128)
        hipLaunchKernelGGL(mgemm_kernel, dim3(NPTS / MBM, DM / MBN), dim3(256), 0, stream,
            CSb, 512, 512, (const float*)nullptr, 0,
            WUh + (size_t)l * DM * DH, WUl + (size_t)l * DM * DH, DH,
            updb2 + (size_t)l * DM, DM, h, DM, HSb, DM, 0);
        // h = graph_norm(hn)
        hipLaunchKernelGGL(norm_part_kernel, dim3(BGR, 8), dim3(256), 0, stream, HSb, psum);
        hipLaunchKernelGGL(norm_apply_kernel, dim3(BGR, 8), dim3(256), 0, stream,
            HSb, h, psum, nw + (size_t)l * DM, nb + (size_t)l * DM, nms + (size_t)l * DM);
    }

    // gate hidden = tanh(h @ gW1 + gb1) via MFMA, then dot with gW2
    hipLaunchKernelGGL(mgemm_kernel, dim3(NPTS / MBM, DM / MBN), dim3(256), 0, stream,
        h, DM, DM, (const float*)nullptr, 0,
        WGh, WGl, DM, gb1, DM, (const float*)nullptr, 0, CSb, DM, 2);
    hipLaunchKernelGGL(gate_dot_kernel, dim3(NPTS / 4), dim3(256), 0, stream,
        CSb, gW2, gb2, glb);

    hipLaunchKernelGGL(pool_stats_kernel, dim3(BGR), dim3(256), 0, stream, glb, gstat);
    hipLaunchKernelGGL(pool_part_kernel, dim3(BGR, 8), dim3(256), 0, stream, h, glb, gstat, ppool);
    hipLaunchKernelGGL(pool_head_kernel, dim3(BGR), dim3(128), 0, stream,
        ppool, gstat, hW1, hb1, hW2, hb2, outp);
}